// Round 17
// baseline (814.686 us; speedup 1.0000x reference)
//
#include <hip/hip_runtime.h>
#include <hip/hip_bf16.h>

#define NN 8192
#define DD 256
#define ALPHA 50.0f
#define BETA 1.0f
#define THR 10.0f
#define KQ 8                 // key splits
#define KEYS (NN / KQ)       // 1024 keys per split
#define KTILE 64             // keys per iteration (2 sub-steps of 32)
#define ITERS (KEYS / KTILE) // 16
#define QROWS 256            // q-rows per block (8 waves x 32: 2 subtiles of 16)

typedef __attribute__((ext_vector_type(8))) short short8;
typedef __attribute__((ext_vector_type(4))) float f32x4;

static __device__ __forceinline__ ushort f2bf(float f) {
    union { __hip_bfloat16 h; ushort u; } v;
    v.h = __float2bfloat16(f);
    return v.u;
}
static __device__ __forceinline__ float bf2f(ushort u) {
    union { unsigned u; float f; } v; v.u = ((unsigned)u) << 16;
    return v.f;
}
static __device__ __forceinline__ void gl_lds16(const void* g, void* l) {
    __builtin_amdgcn_global_load_lds(
        (const __attribute__((address_space(1))) unsigned int*)g,
        (__attribute__((address_space(3))) unsigned int*)l, 16, 0, 0);
}

// --- W f32 -> bf16, once ---
__global__ void k_wconv(const float* __restrict__ W, ushort* __restrict__ Wb) {
    int i = blockIdx.x * 256 + threadIdx.x;
    Wb[i] = f2bf(W[i]);
}

// --- bitpack mask: bits[row][col/32]; float4 loads + LDS nibble assembly ---
__global__ __launch_bounds__(256) void k_pack(const float* __restrict__ sim,
                                              unsigned* __restrict__ bits) {
    __shared__ unsigned char nibs[256];
    int row = blockIdx.x;
    int tid = threadIdx.x;
    for (int p = 0; p < 8; ++p) {
        int col = p * 1024 + tid * 4;
        float4 v = *reinterpret_cast<const float4*>(sim + (size_t)row * NN + col);
        unsigned char nib = (unsigned char)((v.x != 0.f) | ((v.y != 0.f) << 1) |
                                            ((v.z != 0.f) << 2) | ((v.w != 0.f) << 3));
        nibs[tid] = nib;
        __syncthreads();
        if (tid < 32) {
            unsigned word = 0;
#pragma unroll
            for (int i = 0; i < 8; ++i) word |= ((unsigned)nibs[tid * 8 + i]) << (4 * i);
            bits[row * (NN / 32) + p * 32 + tid] = word;
        }
        __syncthreads();
    }
}

// --- H f32 -> Hv bf16 (row-major) and Hvt bf16 (transposed [D][N]) ---
__global__ __launch_bounds__(256) void k_convert(const float* __restrict__ H,
                                                 ushort* __restrict__ Hv,
                                                 ushort* __restrict__ Hvt) {
    __shared__ ushort T[64][72];
    int tile = blockIdx.x;
    int r0 = (tile >> 2) * 64;
    int c0 = (tile & 3) * 64;
    int tid = threadIdx.x;
    int tr = tid >> 4;
    int tc = (tid & 15) * 4;
    for (int i = 0; i < 4; ++i) {
        int r = tr + i * 16;
        float4 v = *reinterpret_cast<const float4*>(H + (size_t)(r0 + r) * DD + c0 + tc);
        ushort4 o;
        o.x = f2bf(v.x); o.y = f2bf(v.y); o.z = f2bf(v.z); o.w = f2bf(v.w);
        *reinterpret_cast<ushort4*>(Hv + (size_t)(r0 + r) * DD + c0 + tc) = o;
        T[tc + 0][r] = o.x; T[tc + 1][r] = o.y; T[tc + 2][r] = o.z; T[tc + 3][r] = o.w;
    }
    __syncthreads();
    for (int i = 0; i < 4; ++i) {
        int c = tr + i * 16;
        ushort4 o;
        o.x = T[c][tc + 0]; o.y = T[c][tc + 1]; o.z = T[c][tc + 2]; o.w = T[c][tc + 3];
        *reinterpret_cast<ushort4*>(Hvt + (size_t)(c0 + c) * NN + r0 + tc) = o;
    }
}

// --- Hp = bf16(Hv @ W^T + b) ---
__global__ __launch_bounds__(256) void k_proj(const ushort* __restrict__ Hv,
                                              const ushort* __restrict__ Wb,
                                              const float* __restrict__ b,
                                              ushort* __restrict__ Hp) {
    int w = threadIdx.x >> 6;
    int lane = threadIdx.x & 63;
    int row0 = (blockIdx.x >> 1) * 64 + w * 16;
    int ch = blockIdx.x & 1;
    int lr = lane & 15;
    int lk = lane >> 4;
    short8 af[8];
    for (int kk = 0; kk < 8; ++kk)
        af[kk] = *reinterpret_cast<const short8*>(Hv + (size_t)(row0 + lr) * DD + kk * 32 + lk * 8);
    for (int t = 0; t < 8; ++t) {
        f32x4 acc = {0.f, 0.f, 0.f, 0.f};
        int col = (ch * 8 + t) * 16 + lr;
        for (int kk = 0; kk < 8; ++kk) {
            short8 bf = *reinterpret_cast<const short8*>(Wb + (size_t)col * DD + kk * 32 + lk * 8);
            acc = __builtin_amdgcn_mfma_f32_16x16x32_bf16(af[kk], bf, acc, 0, 0, 0);
        }
        float bias = b[col];
        for (int j = 0; j < 4; ++j) {
            int row = row0 + lk * 4 + j;
            Hp[(size_t)row * DD + col] = f2bf(acc[j] + bias);
        }
    }
}

// --- fused masked flash attention: 2 q-subtiles per wave share every K/V
// LDS read (halves LDS bytes per output row -- the binding pipe), 64-key
// iters (A/B ILP), double-buffered tiles, R15 stage-at-start schedule.
// grid = 256: kq = bid&7 (XCD-local), qt = bid>>3 (256 q-rows, 8 waves x 32).
#define PSTR 40
#define KBYTES (KTILE * 256 * 2)          // 32768
#define VBYTES (256 * KTILE * 2)          // 32768
#define PBYTES (8 * 2 * 16 * PSTR * 2)    // 20480
#define SMEM_ATTN (2 * KBYTES + 2 * VBYTES + PBYTES)   // 151552 -> 1 block/CU
__global__ __launch_bounds__(512) void k_attn(const ushort* __restrict__ Hp,
                                              const ushort* __restrict__ Hvt,
                                              const unsigned* __restrict__ bits,
                                              ushort* __restrict__ Opart,
                                              float* __restrict__ mpart,
                                              float* __restrict__ lpart) {
    extern __shared__ char smem[];
    ushort* KlB = (ushort*)smem;                          // 2 x [64][256] swizzled
    ushort* VlB = (ushort*)(smem + 2 * KBYTES);           // 2 x [256][64] swizzled
    ushort* Pl  = (ushort*)(smem + 2 * KBYTES + 2 * VBYTES);

    const int tid = threadIdx.x;
    const int w = tid >> 6;
    const int lane = tid & 63;
    const int lr = lane & 15;
    const int lk = lane >> 4;
    const int bid = blockIdx.x;
    const int kq = bid & 7;
    const int qt = bid >> 3;
    const int rw0 = qt * QROWS + w * 32;   // subtile A rows; B = +16
    const int kstart = kq * KEYS;

    // ---- loop-invariant staging offsets (2048 16B slots each, 4 insts/thread) ----
    int kSrc[4], vSrc[4], dstO[4];
#pragma unroll
    for (int i = 0; i < 4; ++i) {
        int S = i * 512 + tid;
        int rK = S >> 5, cpK = S & 31;
        kSrc[i] = rK * 256 + (cpK ^ (rK & 7)) * 8;
        int rV = S >> 3, cpV = S & 7;
        vSrc[i] = rV * NN + (cpV ^ (rV & 7)) * 8;
        dstO[i] = S * 8;
    }
    auto stageK = [&](int buf, int kb) {
        const ushort* Kg = Hp + (size_t)kb * DD;
        ushort* base = KlB + buf * (KTILE * 256);
#pragma unroll
        for (int i = 0; i < 4; ++i) gl_lds16(Kg + kSrc[i], base + dstO[i]);
    };
    auto stageV = [&](int buf, int kb) {
        const ushort* Vg = Hvt + kb;
        ushort* base = VlB + buf * (256 * KTILE);
#pragma unroll
        for (int i = 0; i < 4; ++i) gl_lds16(Vg + vSrc[i], base + dstO[i]);
    };

    // ---- loop-invariant LDS read offsets (bytes) ----
    int Koff[8];
#pragma unroll
    for (int kk = 0; kk < 8; ++kk)
        Koff[kk] = (lr << 9) + ((((kk << 2) + lk) ^ (lr & 7)) << 4);
    const int vBaseA = (lr << 7) + ((lk ^ (lr & 7)) << 4);
    const int vBaseB = (lr << 7) + (((4 + lk) ^ (lr & 7)) << 4);

    short8 qfA[8], qfB[8];
#pragma unroll
    for (int kk = 0; kk < 8; ++kk) {
        qfA[kk] = *reinterpret_cast<const short8*>(Hp + (size_t)(rw0 + lr) * DD + kk * 32 + lk * 8);
        qfB[kk] = *reinterpret_cast<const short8*>(Hp + (size_t)(rw0 + 16 + lr) * DD + kk * 32 + lk * 8);
    }

    f32x4 oA[17], oB[17];
#pragma unroll
    for (int t = 0; t < 17; ++t) { oA[t] = {0.f,0.f,0.f,0.f}; oB[t] = {0.f,0.f,0.f,0.f}; }
    float mA[4] = {-1e30f, -1e30f, -1e30f, -1e30f};
    float mB[4] = {-1e30f, -1e30f, -1e30f, -1e30f};

    short8 ones;
#pragma unroll
    for (int e = 0; e < 8; ++e) ones[e] = (short)0x3f80;  // bf16 1.0

    // ---- prologue: stage tile 0 ----
    stageK(0, kstart);
    stageV(0, kstart);
    asm volatile("s_waitcnt vmcnt(0)" ::: "memory");
    __builtin_amdgcn_s_barrier();
    __builtin_amdgcn_sched_barrier(0);

    ushort* PwA = Pl + (size_t)(w * 2) * 16 * PSTR;
    ushort* PwB = PwA + 16 * PSTR;
    const int rbA = (rw0 + lk * 4) * (NN / 32);
    const int rbB = rbA + 16 * (NN / 32);
    int cur = 0;
    for (int it = 0; it < ITERS; ++it) {
        const int kb = kstart + it * KTILE;
        if (it + 1 < ITERS) {       // stage next tile into other buffer
            stageK(cur ^ 1, kb + KTILE);
            stageV(cur ^ 1, kb + KTILE);
        }
        const int wi = kb >> 5;
        unsigned mAa[4], mAb[4], mBa[4], mBb[4];
#pragma unroll
        for (int j = 0; j < 4; ++j) {
            mAa[j] = bits[rbA + j * (NN / 32) + wi];
            mAb[j] = bits[rbA + j * (NN / 32) + wi + 1];
            mBa[j] = bits[rbB + j * (NN / 32) + wi];
            mBb[j] = bits[rbB + j * (NN / 32) + wi + 1];
        }

        // ---- QK^T: each K fragment feeds BOTH subtiles (8 indep chains) ----
        const char* Kb = (const char*)(KlB + cur * (KTILE * 256));
        f32x4 sA0a = {0.f,0.f,0.f,0.f}, sA1a = {0.f,0.f,0.f,0.f};
        f32x4 sA0b = {0.f,0.f,0.f,0.f}, sA1b = {0.f,0.f,0.f,0.f};
        f32x4 sB0a = {0.f,0.f,0.f,0.f}, sB1a = {0.f,0.f,0.f,0.f};
        f32x4 sB0b = {0.f,0.f,0.f,0.f}, sB1b = {0.f,0.f,0.f,0.f};
        __builtin_amdgcn_s_setprio(1);
#pragma unroll
        for (int kk = 0; kk < 8; ++kk) {
            short8 k0a = *reinterpret_cast<const short8*>(Kb + Koff[kk]);
            short8 k1a = *reinterpret_cast<const short8*>(Kb + Koff[kk] + (16 << 9));
            short8 k0b = *reinterpret_cast<const short8*>(Kb + Koff[kk] + (32 << 9));
            short8 k1b = *reinterpret_cast<const short8*>(Kb + Koff[kk] + (48 << 9));
            sA0a = __builtin_amdgcn_mfma_f32_16x16x32_bf16(qfA[kk], k0a, sA0a, 0, 0, 0);
            sB0a = __builtin_amdgcn_mfma_f32_16x16x32_bf16(qfB[kk], k0a, sB0a, 0, 0, 0);
            sA1a = __builtin_amdgcn_mfma_f32_16x16x32_bf16(qfA[kk], k1a, sA1a, 0, 0, 0);
            sB1a = __builtin_amdgcn_mfma_f32_16x16x32_bf16(qfB[kk], k1a, sB1a, 0, 0, 0);
            sA0b = __builtin_amdgcn_mfma_f32_16x16x32_bf16(qfA[kk], k0b, sA0b, 0, 0, 0);
            sB0b = __builtin_amdgcn_mfma_f32_16x16x32_bf16(qfB[kk], k0b, sB0b, 0, 0, 0);
            sA1b = __builtin_amdgcn_mfma_f32_16x16x32_bf16(qfA[kk], k1b, sA1b, 0, 0, 0);
            sB1b = __builtin_amdgcn_mfma_f32_16x16x32_bf16(qfB[kk], k1b, sB1b, 0, 0, 0);
        }
        __builtin_amdgcn_s_setprio(0);

        const char* Vb = (const char*)(VlB + cur * (256 * KTILE));
        // ================= sub-step a (keys kb..kb+31) =================
        {
            float c = -1e30f;
#pragma unroll
            for (int j = 0; j < 4; ++j) {
                float x0 = ((mAa[j] >> lr) & 1u) ? sA0a[j] : -1e30f;
                float x1 = ((mAa[j] >> (lr + 16)) & 1u) ? sA1a[j] : -1e30f;
                sA0a[j] = x0; sA1a[j] = x1;
                c = fmaxf(c, fmaxf(x0, x1) - mA[j]);
                float y0 = ((mBa[j] >> lr) & 1u) ? sB0a[j] : -1e30f;
                float y1 = ((mBa[j] >> (lr + 16)) & 1u) ? sB1a[j] : -1e30f;
                sB0a[j] = y0; sB1a[j] = y1;
                c = fmaxf(c, fmaxf(y0, y1) - mB[j]);
            }
            if (__any(c > THR)) {
#pragma unroll
                for (int j = 0; j < 4; ++j) {
                    float mx = fmaxf(sA0a[j], sA1a[j]);
                    mx = fmaxf(mx, __shfl_xor(mx, 1));
                    mx = fmaxf(mx, __shfl_xor(mx, 2));
                    mx = fmaxf(mx, __shfl_xor(mx, 4));
                    mx = fmaxf(mx, __shfl_xor(mx, 8));
                    float mn = fmaxf(mA[j], mx);
                    float sc = __expf(mA[j] - mn);
                    mA[j] = mn;
#pragma unroll
                    for (int t = 0; t < 17; ++t) oA[t][j] *= sc;
                    float my = fmaxf(sB0a[j], sB1a[j]);
                    my = fmaxf(my, __shfl_xor(my, 1));
                    my = fmaxf(my, __shfl_xor(my, 2));
                    my = fmaxf(my, __shfl_xor(my, 4));
                    my = fmaxf(my, __shfl_xor(my, 8));
                    float mn2 = fmaxf(mB[j], my);
                    float sc2 = __expf(mB[j] - mn2);
                    mB[j] = mn2;
#pragma unroll
                    for (int t = 0; t < 17; ++t) oB[t][j] *= sc2;
                }
            }
#pragma unroll
            for (int j = 0; j < 4; ++j) {
                PwA[(lk * 4 + j) * PSTR + lr]      = f2bf(__expf(sA0a[j] - mA[j]));
                PwA[(lk * 4 + j) * PSTR + 16 + lr] = f2bf(__expf(sA1a[j] - mA[j]));
                PwB[(lk * 4 + j) * PSTR + lr]      = f2bf(__expf(sB0a[j] - mB[j]));
                PwB[(lk * 4 + j) * PSTR + 16 + lr] = f2bf(__expf(sB1a[j] - mB[j]));
            }
            asm volatile("s_waitcnt lgkmcnt(0)" ::: "memory");
            __builtin_amdgcn_sched_barrier(0);
            short8 paA = *reinterpret_cast<const short8*>(PwA + lr * PSTR + lk * 8);
            short8 paB = *reinterpret_cast<const short8*>(PwB + lr * PSTR + lk * 8);
            __builtin_amdgcn_s_setprio(1);
#pragma unroll
            for (int t = 0; t < 16; ++t) {
                short8 vf = *reinterpret_cast<const short8*>(Vb + vBaseA + (t << 11));
                oA[t] = __builtin_amdgcn_mfma_f32_16x16x32_bf16(paA, vf, oA[t], 0, 0, 0);
                oB[t] = __builtin_amdgcn_mfma_f32_16x16x32_bf16(paB, vf, oB[t], 0, 0, 0);
            }
            oA[16] = __builtin_amdgcn_mfma_f32_16x16x32_bf16(paA, ones, oA[16], 0, 0, 0);
            oB[16] = __builtin_amdgcn_mfma_f32_16x16x32_bf16(paB, ones, oB[16], 0, 0, 0);
            __builtin_amdgcn_s_setprio(0);
        }
        // ================= sub-step b (keys kb+32..kb+63) =================
        {
            float c = -1e30f;
#pragma unroll
            for (int j = 0; j < 4; ++j) {
                float x0 = ((mAb[j] >> lr) & 1u) ? sA0b[j] : -1e30f;
                float x1 = ((mAb[j] >> (lr + 16)) & 1u) ? sA1b[j] : -1e30f;
                sA0b[j] = x0; sA1b[j] = x1;
                c = fmaxf(c, fmaxf(x0, x1) - mA[j]);
                float y0 = ((mBb[j] >> lr) & 1u) ? sB0b[j] : -1e30f;
                float y1 = ((mBb[j] >> (lr + 16)) & 1u) ? sB1b[j] : -1e30f;
                sB0b[j] = y0; sB1b[j] = y1;
                c = fmaxf(c, fmaxf(y0, y1) - mB[j]);
            }
            if (__any(c > THR)) {
#pragma unroll
                for (int j = 0; j < 4; ++j) {
                    float mx = fmaxf(sA0b[j], sA1b[j]);
                    mx = fmaxf(mx, __shfl_xor(mx, 1));
                    mx = fmaxf(mx, __shfl_xor(mx, 2));
                    mx = fmaxf(mx, __shfl_xor(mx, 4));
                    mx = fmaxf(mx, __shfl_xor(mx, 8));
                    float mn = fmaxf(mA[j], mx);
                    float sc = __expf(mA[j] - mn);
                    mA[j] = mn;
#pragma unroll
                    for (int t = 0; t < 17; ++t) oA[t][j] *= sc;
                    float my = fmaxf(sB0b[j], sB1b[j]);
                    my = fmaxf(my, __shfl_xor(my, 1));
                    my = fmaxf(my, __shfl_xor(my, 2));
                    my = fmaxf(my, __shfl_xor(my, 4));
                    my = fmaxf(my, __shfl_xor(my, 8));
                    float mn2 = fmaxf(mB[j], my);
                    float sc2 = __expf(mB[j] - mn2);
                    mB[j] = mn2;
#pragma unroll
                    for (int t = 0; t < 17; ++t) oB[t][j] *= sc2;
                }
            }
#pragma unroll
            for (int j = 0; j < 4; ++j) {
                PwA[(lk * 4 + j) * PSTR + lr]      = f2bf(__expf(sA0b[j] - mA[j]));
                PwA[(lk * 4 + j) * PSTR + 16 + lr] = f2bf(__expf(sA1b[j] - mA[j]));
                PwB[(lk * 4 + j) * PSTR + lr]      = f2bf(__expf(sB0b[j] - mB[j]));
                PwB[(lk * 4 + j) * PSTR + 16 + lr] = f2bf(__expf(sB1b[j] - mB[j]));
            }
            asm volatile("s_waitcnt lgkmcnt(0)" ::: "memory");
            __builtin_amdgcn_sched_barrier(0);
            short8 paA = *reinterpret_cast<const short8*>(PwA + lr * PSTR + lk * 8);
            short8 paB = *reinterpret_cast<const short8*>(PwB + lr * PSTR + lk * 8);
            __builtin_amdgcn_s_setprio(1);
#pragma unroll
            for (int t = 0; t < 16; ++t) {
                short8 vf = *reinterpret_cast<const short8*>(Vb + vBaseB + (t << 11));
                oA[t] = __builtin_amdgcn_mfma_f32_16x16x32_bf16(paA, vf, oA[t], 0, 0, 0);
                oB[t] = __builtin_amdgcn_mfma_f32_16x16x32_bf16(paB, vf, oB[t], 0, 0, 0);
            }
            oA[16] = __builtin_amdgcn_mfma_f32_16x16x32_bf16(paA, ones, oA[16], 0, 0, 0);
            oB[16] = __builtin_amdgcn_mfma_f32_16x16x32_bf16(paB, ones, oB[16], 0, 0, 0);
            __builtin_amdgcn_s_setprio(0);
        }
        // end of iter: next tile (staged at iter start) must be resident
        if (it + 1 < ITERS) {
            asm volatile("s_waitcnt vmcnt(0)" ::: "memory");
            __builtin_amdgcn_s_barrier();
            __builtin_amdgcn_sched_barrier(0);
        }
        cur ^= 1;
    }

    // ---- write split-K partials (both subtiles) ----
    ushort* opA = Opart + ((size_t)kq * NN + rw0) * DD;
    ushort* opB = opA + (size_t)16 * DD;
#pragma unroll
    for (int t = 0; t < 16; ++t)
#pragma unroll
        for (int j = 0; j < 4; ++j) {
            opA[(size_t)(lk * 4 + j) * DD + t * 16 + lr] = f2bf(oA[t][j]);
            opB[(size_t)(lk * 4 + j) * DD + t * 16 + lr] = f2bf(oB[t][j]);
        }
    if (lr == 0) {
#pragma unroll
        for (int j = 0; j < 4; ++j) {
            mpart[kq * NN + rw0 + lk * 4 + j] = mA[j];
            lpart[kq * NN + rw0 + lk * 4 + j] = oA[16][j];
            mpart[kq * NN + rw0 + 16 + lk * 4 + j] = mB[j];
            lpart[kq * NN + rw0 + 16 + lk * 4 + j] = oB[16][j];
        }
    }
}

// --- merge 8 split-K partials + CRF epilogue ---
__global__ __launch_bounds__(256) void k_merge8(const ushort* __restrict__ Opart,
                                                const float* __restrict__ mpart,
                                                const float* __restrict__ lpart,
                                                const float* __restrict__ Qo,
                                                float* __restrict__ dst) {
    int w = threadIdx.x >> 6;
    int lane = threadIdx.x & 63;
    int r0 = blockIdx.x * 32 + w * 8;
    for (int rr = 0; rr < 8; ++rr) {
        int r = r0 + rr;
        float mv[8], f[8];
        float M = -1e30f;
#pragma unroll
        for (int p = 0; p < 8; ++p) { mv[p] = mpart[p * NN + r]; M = fmaxf(M, mv[p]); }
        float L = 0.f;
#pragma unroll
        for (int p = 0; p < 8; ++p) { f[p] = __expf(mv[p] - M); L += f[p] * lpart[p * NN + r]; }
        float invL = 1.0f / L;
        int c = lane * 4;
        float a0 = 0.f, a1 = 0.f, a2 = 0.f, a3 = 0.f;
#pragma unroll
        for (int p = 0; p < 8; ++p) {
            ushort4 u = *reinterpret_cast<const ushort4*>(Opart + ((size_t)p * NN + r) * DD + c);
            a0 += f[p] * bf2f(u.x); a1 += f[p] * bf2f(u.y);
            a2 += f[p] * bf2f(u.z); a3 += f[p] * bf2f(u.w);
        }
        float4 qv = *reinterpret_cast<const float4*>(Qo + (size_t)r * DD + c);
        float4 ov;
        ov.x = (ALPHA * qv.x + a0 * invL) * (1.0f / (ALPHA + BETA));
        ov.y = (ALPHA * qv.y + a1 * invL) * (1.0f / (ALPHA + BETA));
        ov.z = (ALPHA * qv.z + a2 * invL) * (1.0f / (ALPHA + BETA));
        ov.w = (ALPHA * qv.w + a3 * invL) * (1.0f / (ALPHA + BETA));
        *reinterpret_cast<float4*>(dst + (size_t)r * DD + c) = ov;
    }
}

extern "C" void kernel_launch(void* const* d_in, const int* in_sizes, int n_in,
                              void* d_out, int out_size, void* d_ws, size_t ws_size,
                              hipStream_t stream) {
    const float* Q   = (const float*)d_in[0];
    const float* sim = (const float*)d_in[1];
    const float* W   = (const float*)d_in[2];
    const float* b   = (const float*)d_in[3];
    float* out = (float*)d_out;

    char* ws = (char*)d_ws;
    size_t off = 0;
    ushort* Hv   = (ushort*)(ws + off); off += (size_t)NN * DD * 2;
    ushort* HvtA = (ushort*)(ws + off); off += (size_t)NN * DD * 2;
    ushort* HvtB = (ushort*)(ws + off); off += (size_t)NN * DD * 2;
    ushort* Hp   = (ushort*)(ws + off); off += (size_t)NN * DD * 2;
    ushort* Wb   = (ushort*)(ws + off); off += (size_t)DD * DD * 2;
    unsigned* bits = (unsigned*)(ws + off); off += (size_t)NN * (NN / 32) * 4;
    float*  H1   = (float*)(ws + off);  off += (size_t)NN * DD * 4;
    ushort* Opart = (ushort*)(ws + off); off += (size_t)KQ * NN * DD * 2;
    float*  mpart = (float*)(ws + off);  off += (size_t)KQ * NN * 4;
    float*  lpart = (float*)(ws + off);  off += (size_t)KQ * NN * 4;

    (void)hipFuncSetAttribute((const void*)k_attn,
                              hipFuncAttributeMaxDynamicSharedMemorySize, SMEM_ATTN);

    k_wconv<<<DD * DD / 256, 256, 0, stream>>>(W, Wb);
    k_pack<<<NN, 256, 0, stream>>>(sim, bits);
    k_convert<<<(NN / 64) * (DD / 64), 256, 0, stream>>>(Q, Hv, HvtA);

    // iter 1: V = Q (HvtA)
    k_proj<<<NN / 32, 256, 0, stream>>>(Hv, Wb, b, Hp);
    k_attn<<<(NN / QROWS) * KQ, 512, SMEM_ATTN, stream>>>(Hp, HvtA, bits, Opart, mpart, lpart);
    k_merge8<<<NN / 32, 256, 0, stream>>>(Opart, mpart, lpart, Q, H1);
    k_convert<<<(NN / 64) * (DD / 64), 256, 0, stream>>>(H1, Hv, HvtB);

    // iter 2: V = H1 (HvtB)
    k_proj<<<NN / 32, 256, 0, stream>>>(Hv, Wb, b, Hp);
    k_attn<<<(NN / QROWS) * KQ, 512, SMEM_ATTN, stream>>>(Hp, HvtB, bits, Opart, mpart, lpart);
    k_merge8<<<NN / 32, 256, 0, stream>>>(Opart, mpart, lpart, Q, out);
}

// Round 18
// 794.825 us; speedup vs baseline: 1.0250x; 1.0250x over previous
//
#include <hip/hip_runtime.h>
#include <hip/hip_bf16.h>

#define NN 8192
#define DD 256
#define ALPHA 50.0f
#define BETA 1.0f
#define THR 10.0f
#define KQ 8                 // key splits
#define KEYS (NN / KQ)       // 1024 keys per split
#define KTILE 64             // keys per iteration (2 sub-steps of 32)
#define ITERS (KEYS / KTILE) // 16
#define QROWS 256            // q-rows per block (8 waves x 32: 2 subtiles of 16)

typedef __attribute__((ext_vector_type(8))) short short8;
typedef __attribute__((ext_vector_type(4))) float f32x4;

static __device__ __forceinline__ ushort f2bf(float f) {
    union { __hip_bfloat16 h; ushort u; } v;
    v.h = __float2bfloat16(f);
    return v.u;
}
static __device__ __forceinline__ float bf2f(ushort u) {
    union { unsigned u; float f; } v; v.u = ((unsigned)u) << 16;
    return v.f;
}
static __device__ __forceinline__ void gl_lds16(const void* g, void* l) {
    __builtin_amdgcn_global_load_lds(
        (const __attribute__((address_space(1))) unsigned int*)g,
        (__attribute__((address_space(3))) unsigned int*)l, 16, 0, 0);
}

// --- W f32 -> bf16, once ---
__global__ void k_wconv(const float* __restrict__ W, ushort* __restrict__ Wb) {
    int i = blockIdx.x * 256 + threadIdx.x;
    Wb[i] = f2bf(W[i]);
}

// --- bitpack mask: bits[row][col/32]; float4 loads + LDS nibble assembly ---
__global__ __launch_bounds__(256) void k_pack(const float* __restrict__ sim,
                                              unsigned* __restrict__ bits) {
    __shared__ unsigned char nibs[256];
    int row = blockIdx.x;
    int tid = threadIdx.x;
    for (int p = 0; p < 8; ++p) {
        int col = p * 1024 + tid * 4;
        float4 v = *reinterpret_cast<const float4*>(sim + (size_t)row * NN + col);
        unsigned char nib = (unsigned char)((v.x != 0.f) | ((v.y != 0.f) << 1) |
                                            ((v.z != 0.f) << 2) | ((v.w != 0.f) << 3));
        nibs[tid] = nib;
        __syncthreads();
        if (tid < 32) {
            unsigned word = 0;
#pragma unroll
            for (int i = 0; i < 8; ++i) word |= ((unsigned)nibs[tid * 8 + i]) << (4 * i);
            bits[row * (NN / 32) + p * 32 + tid] = word;
        }
        __syncthreads();
    }
}

// --- H f32 -> Hv bf16 (row-major) and Hvt bf16 (transposed [D][N]) ---
__global__ __launch_bounds__(256) void k_convert(const float* __restrict__ H,
                                                 ushort* __restrict__ Hv,
                                                 ushort* __restrict__ Hvt) {
    __shared__ ushort T[64][72];
    int tile = blockIdx.x;
    int r0 = (tile >> 2) * 64;
    int c0 = (tile & 3) * 64;
    int tid = threadIdx.x;
    int tr = tid >> 4;
    int tc = (tid & 15) * 4;
    for (int i = 0; i < 4; ++i) {
        int r = tr + i * 16;
        float4 v = *reinterpret_cast<const float4*>(H + (size_t)(r0 + r) * DD + c0 + tc);
        ushort4 o;
        o.x = f2bf(v.x); o.y = f2bf(v.y); o.z = f2bf(v.z); o.w = f2bf(v.w);
        *reinterpret_cast<ushort4*>(Hv + (size_t)(r0 + r) * DD + c0 + tc) = o;
        T[tc + 0][r] = o.x; T[tc + 1][r] = o.y; T[tc + 2][r] = o.z; T[tc + 3][r] = o.w;
    }
    __syncthreads();
    for (int i = 0; i < 4; ++i) {
        int c = tr + i * 16;
        ushort4 o;
        o.x = T[c][tc + 0]; o.y = T[c][tc + 1]; o.z = T[c][tc + 2]; o.w = T[c][tc + 3];
        *reinterpret_cast<ushort4*>(Hvt + (size_t)(c0 + c) * NN + r0 + tc) = o;
    }
}

// --- Hp = bf16(Hv @ W^T + b) ---
__global__ __launch_bounds__(256) void k_proj(const ushort* __restrict__ Hv,
                                              const ushort* __restrict__ Wb,
                                              const float* __restrict__ b,
                                              ushort* __restrict__ Hp) {
    int w = threadIdx.x >> 6;
    int lane = threadIdx.x & 63;
    int row0 = (blockIdx.x >> 1) * 64 + w * 16;
    int ch = blockIdx.x & 1;
    int lr = lane & 15;
    int lk = lane >> 4;
    short8 af[8];
    for (int kk = 0; kk < 8; ++kk)
        af[kk] = *reinterpret_cast<const short8*>(Hv + (size_t)(row0 + lr) * DD + kk * 32 + lk * 8);
    for (int t = 0; t < 8; ++t) {
        f32x4 acc = {0.f, 0.f, 0.f, 0.f};
        int col = (ch * 8 + t) * 16 + lr;
        for (int kk = 0; kk < 8; ++kk) {
            short8 bf = *reinterpret_cast<const short8*>(Wb + (size_t)col * DD + kk * 32 + lk * 8);
            acc = __builtin_amdgcn_mfma_f32_16x16x32_bf16(af[kk], bf, acc, 0, 0, 0);
        }
        float bias = b[col];
        for (int j = 0; j < 4; ++j) {
            int row = row0 + lk * 4 + j;
            Hp[(size_t)row * DD + col] = f2bf(acc[j] + bias);
        }
    }
}

// --- fused masked flash attention: 2 q-subtiles per wave share every K/V LDS
// read; QK computed per sub-step (4 chains) to fit the 256-VGPR budget;
// __launch_bounds__(512,2) prevents the R17 spill (VGPR cap 128 -> 256).
// grid = 256: kq = bid&7 (XCD-local), qt = bid>>3 (256 q-rows, 8 waves x 32).
#define PSTR 40
#define KBYTES (KTILE * 256 * 2)          // 32768
#define VBYTES (256 * KTILE * 2)          // 32768
#define PBYTES (8 * 2 * 16 * PSTR * 2)    // 20480
#define SMEM_ATTN (2 * KBYTES + 2 * VBYTES + PBYTES)   // 151552 -> 1 block/CU
__global__ __launch_bounds__(512, 2) void k_attn(const ushort* __restrict__ Hp,
                                                 const ushort* __restrict__ Hvt,
                                                 const unsigned* __restrict__ bits,
                                                 ushort* __restrict__ Opart,
                                                 float* __restrict__ mpart,
                                                 float* __restrict__ lpart) {
    extern __shared__ char smem[];
    ushort* KlB = (ushort*)smem;                          // 2 x [64][256] swizzled
    ushort* VlB = (ushort*)(smem + 2 * KBYTES);           // 2 x [256][64] swizzled
    ushort* Pl  = (ushort*)(smem + 2 * KBYTES + 2 * VBYTES);

    const int tid = threadIdx.x;
    const int w = tid >> 6;
    const int lane = tid & 63;
    const int lr = lane & 15;
    const int lk = lane >> 4;
    const int bid = blockIdx.x;
    const int kq = bid & 7;
    const int qt = bid >> 3;
    const int rw0 = qt * QROWS + w * 32;   // subtile A rows; B = +16
    const int kstart = kq * KEYS;

    // ---- loop-invariant staging offsets (2048 16B slots each, 4 insts/thread) ----
    int kSrc[4], vSrc[4], dstO[4];
#pragma unroll
    for (int i = 0; i < 4; ++i) {
        int S = i * 512 + tid;
        int rK = S >> 5, cpK = S & 31;
        kSrc[i] = rK * 256 + (cpK ^ (rK & 7)) * 8;
        int rV = S >> 3, cpV = S & 7;
        vSrc[i] = rV * NN + (cpV ^ (rV & 7)) * 8;
        dstO[i] = S * 8;
    }
    auto stageK = [&](int buf, int kb) {
        const ushort* Kg = Hp + (size_t)kb * DD;
        ushort* base = KlB + buf * (KTILE * 256);
#pragma unroll
        for (int i = 0; i < 4; ++i) gl_lds16(Kg + kSrc[i], base + dstO[i]);
    };
    auto stageV = [&](int buf, int kb) {
        const ushort* Vg = Hvt + kb;
        ushort* base = VlB + buf * (256 * KTILE);
#pragma unroll
        for (int i = 0; i < 4; ++i) gl_lds16(Vg + vSrc[i], base + dstO[i]);
    };

    // ---- loop-invariant LDS read offsets (bytes) ----
    int Koff[8];
#pragma unroll
    for (int kk = 0; kk < 8; ++kk)
        Koff[kk] = (lr << 9) + ((((kk << 2) + lk) ^ (lr & 7)) << 4);
    const int vBaseA = (lr << 7) + ((lk ^ (lr & 7)) << 4);
    const int vBaseB = (lr << 7) + (((4 + lk) ^ (lr & 7)) << 4);

    short8 qfA[8], qfB[8];
#pragma unroll
    for (int kk = 0; kk < 8; ++kk) {
        qfA[kk] = *reinterpret_cast<const short8*>(Hp + (size_t)(rw0 + lr) * DD + kk * 32 + lk * 8);
        qfB[kk] = *reinterpret_cast<const short8*>(Hp + (size_t)(rw0 + 16 + lr) * DD + kk * 32 + lk * 8);
    }

    f32x4 oA[17], oB[17];
#pragma unroll
    for (int t = 0; t < 17; ++t) { oA[t] = {0.f,0.f,0.f,0.f}; oB[t] = {0.f,0.f,0.f,0.f}; }
    float mA[4] = {-1e30f, -1e30f, -1e30f, -1e30f};
    float mB[4] = {-1e30f, -1e30f, -1e30f, -1e30f};

    short8 ones;
#pragma unroll
    for (int e = 0; e < 8; ++e) ones[e] = (short)0x3f80;  // bf16 1.0

    // ---- prologue: stage tile 0 ----
    stageK(0, kstart);
    stageV(0, kstart);
    asm volatile("s_waitcnt vmcnt(0)" ::: "memory");
    __builtin_amdgcn_s_barrier();
    __builtin_amdgcn_sched_barrier(0);

    ushort* PwA = Pl + (size_t)(w * 2) * 16 * PSTR;
    ushort* PwB = PwA + 16 * PSTR;
    const int rbA = (rw0 + lk * 4) * (NN / 32);
    const int rbB = rbA + 16 * (NN / 32);
    int cur = 0;
    for (int it = 0; it < ITERS; ++it) {
        const int kb = kstart + it * KTILE;
        if (it + 1 < ITERS) {       // stage next tile into other buffer
            stageK(cur ^ 1, kb + KTILE);
            stageV(cur ^ 1, kb + KTILE);
        }
        const int wi = kb >> 5;
        const char* Kb = (const char*)(KlB + cur * (KTILE * 256));
        const char* Vb = (const char*)(VlB + cur * (256 * KTILE));

        // ================= sub-step a (keys kb..kb+31) =================
        {
            f32x4 sA0 = {0.f,0.f,0.f,0.f}, sA1 = {0.f,0.f,0.f,0.f};
            f32x4 sB0 = {0.f,0.f,0.f,0.f}, sB1 = {0.f,0.f,0.f,0.f};
            __builtin_amdgcn_s_setprio(1);
#pragma unroll
            for (int kk = 0; kk < 8; ++kk) {
                short8 k0 = *reinterpret_cast<const short8*>(Kb + Koff[kk]);
                short8 k1 = *reinterpret_cast<const short8*>(Kb + Koff[kk] + (16 << 9));
                sA0 = __builtin_amdgcn_mfma_f32_16x16x32_bf16(qfA[kk], k0, sA0, 0, 0, 0);
                sB0 = __builtin_amdgcn_mfma_f32_16x16x32_bf16(qfB[kk], k0, sB0, 0, 0, 0);
                sA1 = __builtin_amdgcn_mfma_f32_16x16x32_bf16(qfA[kk], k1, sA1, 0, 0, 0);
                sB1 = __builtin_amdgcn_mfma_f32_16x16x32_bf16(qfB[kk], k1, sB1, 0, 0, 0);
            }
            __builtin_amdgcn_s_setprio(0);
            unsigned mwA[4], mwB[4];
#pragma unroll
            for (int j = 0; j < 4; ++j) {
                mwA[j] = bits[rbA + j * (NN / 32) + wi];
                mwB[j] = bits[rbB + j * (NN / 32) + wi];
            }
            float c = -1e30f;
#pragma unroll
            for (int j = 0; j < 4; ++j) {
                float x0 = ((mwA[j] >> lr) & 1u) ? sA0[j] : -1e30f;
                float x1 = ((mwA[j] >> (lr + 16)) & 1u) ? sA1[j] : -1e30f;
                sA0[j] = x0; sA1[j] = x1;
                c = fmaxf(c, fmaxf(x0, x1) - mA[j]);
                float y0 = ((mwB[j] >> lr) & 1u) ? sB0[j] : -1e30f;
                float y1 = ((mwB[j] >> (lr + 16)) & 1u) ? sB1[j] : -1e30f;
                sB0[j] = y0; sB1[j] = y1;
                c = fmaxf(c, fmaxf(y0, y1) - mB[j]);
            }
            if (__any(c > THR)) {
#pragma unroll
                for (int j = 0; j < 4; ++j) {
                    float mx = fmaxf(sA0[j], sA1[j]);
                    mx = fmaxf(mx, __shfl_xor(mx, 1));
                    mx = fmaxf(mx, __shfl_xor(mx, 2));
                    mx = fmaxf(mx, __shfl_xor(mx, 4));
                    mx = fmaxf(mx, __shfl_xor(mx, 8));
                    float mn = fmaxf(mA[j], mx);
                    float sc = __expf(mA[j] - mn);
                    mA[j] = mn;
#pragma unroll
                    for (int t = 0; t < 17; ++t) oA[t][j] *= sc;
                    float my = fmaxf(sB0[j], sB1[j]);
                    my = fmaxf(my, __shfl_xor(my, 1));
                    my = fmaxf(my, __shfl_xor(my, 2));
                    my = fmaxf(my, __shfl_xor(my, 4));
                    my = fmaxf(my, __shfl_xor(my, 8));
                    float mn2 = fmaxf(mB[j], my);
                    float sc2 = __expf(mB[j] - mn2);
                    mB[j] = mn2;
#pragma unroll
                    for (int t = 0; t < 17; ++t) oB[t][j] *= sc2;
                }
            }
#pragma unroll
            for (int j = 0; j < 4; ++j) {
                PwA[(lk * 4 + j) * PSTR + lr]      = f2bf(__expf(sA0[j] - mA[j]));
                PwA[(lk * 4 + j) * PSTR + 16 + lr] = f2bf(__expf(sA1[j] - mA[j]));
                PwB[(lk * 4 + j) * PSTR + lr]      = f2bf(__expf(sB0[j] - mB[j]));
                PwB[(lk * 4 + j) * PSTR + 16 + lr] = f2bf(__expf(sB1[j] - mB[j]));
            }
            asm volatile("s_waitcnt lgkmcnt(0)" ::: "memory");
            __builtin_amdgcn_sched_barrier(0);
            short8 paA = *reinterpret_cast<const short8*>(PwA + lr * PSTR + lk * 8);
            short8 paB = *reinterpret_cast<const short8*>(PwB + lr * PSTR + lk * 8);
            __builtin_amdgcn_s_setprio(1);
#pragma unroll
            for (int t = 0; t < 16; ++t) {
                short8 vf = *reinterpret_cast<const short8*>(Vb + vBaseA + (t << 11));
                oA[t] = __builtin_amdgcn_mfma_f32_16x16x32_bf16(paA, vf, oA[t], 0, 0, 0);
                oB[t] = __builtin_amdgcn_mfma_f32_16x16x32_bf16(paB, vf, oB[t], 0, 0, 0);
            }
            oA[16] = __builtin_amdgcn_mfma_f32_16x16x32_bf16(paA, ones, oA[16], 0, 0, 0);
            oB[16] = __builtin_amdgcn_mfma_f32_16x16x32_bf16(paB, ones, oB[16], 0, 0, 0);
            __builtin_amdgcn_s_setprio(0);
        }
        // ================= sub-step b (keys kb+32..kb+63) =================
        {
            f32x4 sA0 = {0.f,0.f,0.f,0.f}, sA1 = {0.f,0.f,0.f,0.f};
            f32x4 sB0 = {0.f,0.f,0.f,0.f}, sB1 = {0.f,0.f,0.f,0.f};
            __builtin_amdgcn_s_setprio(1);
#pragma unroll
            for (int kk = 0; kk < 8; ++kk) {
                short8 k0 = *reinterpret_cast<const short8*>(Kb + Koff[kk] + (32 << 9));
                short8 k1 = *reinterpret_cast<const short8*>(Kb + Koff[kk] + (48 << 9));
                sA0 = __builtin_amdgcn_mfma_f32_16x16x32_bf16(qfA[kk], k0, sA0, 0, 0, 0);
                sB0 = __builtin_amdgcn_mfma_f32_16x16x32_bf16(qfB[kk], k0, sB0, 0, 0, 0);
                sA1 = __builtin_amdgcn_mfma_f32_16x16x32_bf16(qfA[kk], k1, sA1, 0, 0, 0);
                sB1 = __builtin_amdgcn_mfma_f32_16x16x32_bf16(qfB[kk], k1, sB1, 0, 0, 0);
            }
            __builtin_amdgcn_s_setprio(0);
            unsigned mwA[4], mwB[4];
#pragma unroll
            for (int j = 0; j < 4; ++j) {
                mwA[j] = bits[rbA + j * (NN / 32) + wi + 1];
                mwB[j] = bits[rbB + j * (NN / 32) + wi + 1];
            }
            float c = -1e30f;
#pragma unroll
            for (int j = 0; j < 4; ++j) {
                float x0 = ((mwA[j] >> lr) & 1u) ? sA0[j] : -1e30f;
                float x1 = ((mwA[j] >> (lr + 16)) & 1u) ? sA1[j] : -1e30f;
                sA0[j] = x0; sA1[j] = x1;
                c = fmaxf(c, fmaxf(x0, x1) - mA[j]);
                float y0 = ((mwB[j] >> lr) & 1u) ? sB0[j] : -1e30f;
                float y1 = ((mwB[j] >> (lr + 16)) & 1u) ? sB1[j] : -1e30f;
                sB0[j] = y0; sB1[j] = y1;
                c = fmaxf(c, fmaxf(y0, y1) - mB[j]);
            }
            if (__any(c > THR)) {
#pragma unroll
                for (int j = 0; j < 4; ++j) {
                    float mx = fmaxf(sA0[j], sA1[j]);
                    mx = fmaxf(mx, __shfl_xor(mx, 1));
                    mx = fmaxf(mx, __shfl_xor(mx, 2));
                    mx = fmaxf(mx, __shfl_xor(mx, 4));
                    mx = fmaxf(mx, __shfl_xor(mx, 8));
                    float mn = fmaxf(mA[j], mx);
                    float sc = __expf(mA[j] - mn);
                    mA[j] = mn;
#pragma unroll
                    for (int t = 0; t < 17; ++t) oA[t][j] *= sc;
                    float my = fmaxf(sB0[j], sB1[j]);
                    my = fmaxf(my, __shfl_xor(my, 1));
                    my = fmaxf(my, __shfl_xor(my, 2));
                    my = fmaxf(my, __shfl_xor(my, 4));
                    my = fmaxf(my, __shfl_xor(my, 8));
                    float mn2 = fmaxf(mB[j], my);
                    float sc2 = __expf(mB[j] - mn2);
                    mB[j] = mn2;
#pragma unroll
                    for (int t = 0; t < 17; ++t) oB[t][j] *= sc2;
                }
            }
#pragma unroll
            for (int j = 0; j < 4; ++j) {
                PwA[(lk * 4 + j) * PSTR + lr]      = f2bf(__expf(sA0[j] - mA[j]));
                PwA[(lk * 4 + j) * PSTR + 16 + lr] = f2bf(__expf(sA1[j] - mA[j]));
                PwB[(lk * 4 + j) * PSTR + lr]      = f2bf(__expf(sB0[j] - mB[j]));
                PwB[(lk * 4 + j) * PSTR + 16 + lr] = f2bf(__expf(sB1[j] - mB[j]));
            }
            asm volatile("s_waitcnt lgkmcnt(0)" ::: "memory");
            __builtin_amdgcn_sched_barrier(0);
            short8 paA = *reinterpret_cast<const short8*>(PwA + lr * PSTR + lk * 8);
            short8 paB = *reinterpret_cast<const short8*>(PwB + lr * PSTR + lk * 8);
            __builtin_amdgcn_s_setprio(1);
#pragma unroll
            for (int t = 0; t < 16; ++t) {
                short8 vf = *reinterpret_cast<const short8*>(Vb + vBaseB + (t << 11));
                oA[t] = __builtin_amdgcn_mfma_f32_16x16x32_bf16(paA, vf, oA[t], 0, 0, 0);
                oB[t] = __builtin_amdgcn_mfma_f32_16x16x32_bf16(paB, vf, oB[t], 0, 0, 0);
            }
            oA[16] = __builtin_amdgcn_mfma_f32_16x16x32_bf16(paA, ones, oA[16], 0, 0, 0);
            oB[16] = __builtin_amdgcn_mfma_f32_16x16x32_bf16(paB, ones, oB[16], 0, 0, 0);
            __builtin_amdgcn_s_setprio(0);
        }
        // end of iter: next tile (staged at iter start) must be resident
        if (it + 1 < ITERS) {
            asm volatile("s_waitcnt vmcnt(0)" ::: "memory");
            __builtin_amdgcn_s_barrier();
            __builtin_amdgcn_sched_barrier(0);
        }
        cur ^= 1;
    }

    // ---- write split-K partials (both subtiles) ----
    ushort* opA = Opart + ((size_t)kq * NN + rw0) * DD;
    ushort* opB = opA + (size_t)16 * DD;
#pragma unroll
    for (int t = 0; t < 16; ++t)
#pragma unroll
        for (int j = 0; j < 4; ++j) {
            opA[(size_t)(lk * 4 + j) * DD + t * 16 + lr] = f2bf(oA[t][j]);
            opB[(size_t)(lk * 4 + j) * DD + t * 16 + lr] = f2bf(oB[t][j]);
        }
    if (lr == 0) {
#pragma unroll
        for (int j = 0; j < 4; ++j) {
            mpart[kq * NN + rw0 + lk * 4 + j] = mA[j];
            lpart[kq * NN + rw0 + lk * 4 + j] = oA[16][j];
            mpart[kq * NN + rw0 + 16 + lk * 4 + j] = mB[j];
            lpart[kq * NN + rw0 + 16 + lk * 4 + j] = oB[16][j];
        }
    }
}

// --- merge 8 split-K partials + CRF epilogue ---
__global__ __launch_bounds__(256) void k_merge8(const ushort* __restrict__ Opart,
                                                const float* __restrict__ mpart,
                                                const float* __restrict__ lpart,
                                                const float* __restrict__ Qo,
                                                float* __restrict__ dst) {
    int w = threadIdx.x >> 6;
    int lane = threadIdx.x & 63;
    int r0 = blockIdx.x * 32 + w * 8;
    for (int rr = 0; rr < 8; ++rr) {
        int r = r0 + rr;
        float mv[8], f[8];
        float M = -1e30f;
#pragma unroll
        for (int p = 0; p < 8; ++p) { mv[p] = mpart[p * NN + r]; M = fmaxf(M, mv[p]); }
        float L = 0.f;
#pragma unroll
        for (int p = 0; p < 8; ++p) { f[p] = __expf(mv[p] - M); L += f[p] * lpart[p * NN + r]; }
        float invL = 1.0f / L;
        int c = lane * 4;
        float a0 = 0.f, a1 = 0.f, a2 = 0.f, a3 = 0.f;
#pragma unroll
        for (int p = 0; p < 8; ++p) {
            ushort4 u = *reinterpret_cast<const ushort4*>(Opart + ((size_t)p * NN + r) * DD + c);
            a0 += f[p] * bf2f(u.x); a1 += f[p] * bf2f(u.y);
            a2 += f[p] * bf2f(u.z); a3 += f[p] * bf2f(u.w);
        }
        float4 qv = *reinterpret_cast<const float4*>(Qo + (size_t)r * DD + c);
        float4 ov;
        ov.x = (ALPHA * qv.x + a0 * invL) * (1.0f / (ALPHA + BETA));
        ov.y = (ALPHA * qv.y + a1 * invL) * (1.0f / (ALPHA + BETA));
        ov.z = (ALPHA * qv.z + a2 * invL) * (1.0f / (ALPHA + BETA));
        ov.w = (ALPHA * qv.w + a3 * invL) * (1.0f / (ALPHA + BETA));
        *reinterpret_cast<float4*>(dst + (size_t)r * DD + c) = ov;
    }
}

extern "C" void kernel_launch(void* const* d_in, const int* in_sizes, int n_in,
                              void* d_out, int out_size, void* d_ws, size_t ws_size,
                              hipStream_t stream) {
    const float* Q   = (const float*)d_in[0];
    const float* sim = (const float*)d_in[1];
    const float* W   = (const float*)d_in[2];
    const float* b   = (const float*)d_in[3];
    float* out = (float*)d_out;

    char* ws = (char*)d_ws;
    size_t off = 0;
    ushort* Hv   = (ushort*)(ws + off); off += (size_t)NN * DD * 2;
    ushort* HvtA = (ushort*)(ws + off); off += (size_t)NN * DD * 2;
    ushort* HvtB = (ushort*)(ws + off); off += (size_t)NN * DD * 2;
    ushort* Hp   = (ushort*)(ws + off); off += (size_t)NN * DD * 2;
    ushort* Wb   = (ushort*)(ws + off); off += (size_t)DD * DD * 2;
    unsigned* bits = (unsigned*)(ws + off); off += (size_t)NN * (NN / 32) * 4;
    float*  H1   = (float*)(ws + off);  off += (size_t)NN * DD * 4;
    ushort* Opart = (ushort*)(ws + off); off += (size_t)KQ * NN * DD * 2;
    float*  mpart = (float*)(ws + off);  off += (size_t)KQ * NN * 4;
    float*  lpart = (float*)(ws + off);  off += (size_t)KQ * NN * 4;

    (void)hipFuncSetAttribute((const void*)k_attn,
                              hipFuncAttributeMaxDynamicSharedMemorySize, SMEM_ATTN);

    k_wconv<<<DD * DD / 256, 256, 0, stream>>>(W, Wb);
    k_pack<<<NN, 256, 0, stream>>>(sim, bits);
    k_convert<<<(NN / 64) * (DD / 64), 256, 0, stream>>>(Q, Hv, HvtA);

    // iter 1: V = Q (HvtA)
    k_proj<<<NN / 32, 256, 0, stream>>>(Hv, Wb, b, Hp);
    k_attn<<<(NN / QROWS) * KQ, 512, SMEM_ATTN, stream>>>(Hp, HvtA, bits, Opart, mpart, lpart);
    k_merge8<<<NN / 32, 256, 0, stream>>>(Opart, mpart, lpart, Q, H1);
    k_convert<<<(NN / 64) * (DD / 64), 256, 0, stream>>>(H1, Hv, HvtB);

    // iter 2: V = H1 (HvtB)
    k_proj<<<NN / 32, 256, 0, stream>>>(Hv, Wb, b, Hp);
    k_attn<<<(NN / QROWS) * KQ, 512, SMEM_ATTN, stream>>>(Hp, HvtB, bits, Opart, mpart, lpart);
    k_merge8<<<NN / 32, 256, 0, stream>>>(Opart, mpart, lpart, Q, out);
}

// Round 19
// 330.585 us; speedup vs baseline: 2.4644x; 2.4043x over previous
//
#include <hip/hip_runtime.h>
#include <hip/hip_bf16.h>

#define NN 8192
#define DD 256
#define ALPHA 50.0f
#define BETA 1.0f
#define THR 10.0f
#define KQ 8                 // key splits
#define KEYS (NN / KQ)       // 1024 keys per split
#define KTILE 64             // keys per iteration (2 sub-steps of 32)
#define ITERS (KEYS / KTILE) // 16
#define QROWS 128            // q-rows per block (8 waves x 16)

typedef __attribute__((ext_vector_type(8))) short short8;
typedef __attribute__((ext_vector_type(4))) float f32x4;

static __device__ __forceinline__ ushort f2bf(float f) {
    union { __hip_bfloat16 h; ushort u; } v;
    v.h = __float2bfloat16(f);
    return v.u;
}
static __device__ __forceinline__ float bf2f(ushort u) {
    union { unsigned u; float f; } v; v.u = ((unsigned)u) << 16;
    return v.f;
}
static __device__ __forceinline__ void gl_lds16(const void* g, void* l) {
    __builtin_amdgcn_global_load_lds(
        (const __attribute__((address_space(1))) unsigned int*)g,
        (__attribute__((address_space(3))) unsigned int*)l, 16, 0, 0);
}

// --- W f32 -> bf16, once ---
__global__ void k_wconv(const float* __restrict__ W, ushort* __restrict__ Wb) {
    int i = blockIdx.x * 256 + threadIdx.x;
    Wb[i] = f2bf(W[i]);
}

// --- bitpack mask: bits[row][col/32]; float4 loads + LDS nibble assembly ---
__global__ __launch_bounds__(256) void k_pack(const float* __restrict__ sim,
                                              unsigned* __restrict__ bits) {
    __shared__ unsigned char nibs[256];
    int row = blockIdx.x;
    int tid = threadIdx.x;
    for (int p = 0; p < 8; ++p) {
        int col = p * 1024 + tid * 4;
        float4 v = *reinterpret_cast<const float4*>(sim + (size_t)row * NN + col);
        unsigned char nib = (unsigned char)((v.x != 0.f) | ((v.y != 0.f) << 1) |
                                            ((v.z != 0.f) << 2) | ((v.w != 0.f) << 3));
        nibs[tid] = nib;
        __syncthreads();
        if (tid < 32) {
            unsigned word = 0;
#pragma unroll
            for (int i = 0; i < 8; ++i) word |= ((unsigned)nibs[tid * 8 + i]) << (4 * i);
            bits[row * (NN / 32) + p * 32 + tid] = word;
        }
        __syncthreads();
    }
}

// --- H f32 -> Hv bf16 (row-major) and Hvt bf16 (transposed [D][N]) ---
__global__ __launch_bounds__(256) void k_convert(const float* __restrict__ H,
                                                 ushort* __restrict__ Hv,
                                                 ushort* __restrict__ Hvt) {
    __shared__ ushort T[64][72];
    int tile = blockIdx.x;
    int r0 = (tile >> 2) * 64;
    int c0 = (tile & 3) * 64;
    int tid = threadIdx.x;
    int tr = tid >> 4;
    int tc = (tid & 15) * 4;
    for (int i = 0; i < 4; ++i) {
        int r = tr + i * 16;
        float4 v = *reinterpret_cast<const float4*>(H + (size_t)(r0 + r) * DD + c0 + tc);
        ushort4 o;
        o.x = f2bf(v.x); o.y = f2bf(v.y); o.z = f2bf(v.z); o.w = f2bf(v.w);
        *reinterpret_cast<ushort4*>(Hv + (size_t)(r0 + r) * DD + c0 + tc) = o;
        T[tc + 0][r] = o.x; T[tc + 1][r] = o.y; T[tc + 2][r] = o.z; T[tc + 3][r] = o.w;
    }
    __syncthreads();
    for (int i = 0; i < 4; ++i) {
        int c = tr + i * 16;
        ushort4 o;
        o.x = T[c][tc + 0]; o.y = T[c][tc + 1]; o.z = T[c][tc + 2]; o.w = T[c][tc + 3];
        *reinterpret_cast<ushort4*>(Hvt + (size_t)(c0 + c) * NN + r0 + tc) = o;
    }
}

// --- Hp = bf16(Hv @ W^T + b) ---
__global__ __launch_bounds__(256) void k_proj(const ushort* __restrict__ Hv,
                                              const ushort* __restrict__ Wb,
                                              const float* __restrict__ b,
                                              ushort* __restrict__ Hp) {
    int w = threadIdx.x >> 6;
    int lane = threadIdx.x & 63;
    int row0 = (blockIdx.x >> 1) * 64 + w * 16;
    int ch = blockIdx.x & 1;
    int lr = lane & 15;
    int lk = lane >> 4;
    short8 af[8];
    for (int kk = 0; kk < 8; ++kk)
        af[kk] = *reinterpret_cast<const short8*>(Hv + (size_t)(row0 + lr) * DD + kk * 32 + lk * 8);
    for (int t = 0; t < 8; ++t) {
        f32x4 acc = {0.f, 0.f, 0.f, 0.f};
        int col = (ch * 8 + t) * 16 + lr;
        for (int kk = 0; kk < 8; ++kk) {
            short8 bf = *reinterpret_cast<const short8*>(Wb + (size_t)col * DD + kk * 32 + lk * 8);
            acc = __builtin_amdgcn_mfma_f32_16x16x32_bf16(af[kk], bf, acc, 0, 0, 0);
        }
        float bias = b[col];
        for (int j = 0; j < 4; ++j) {
            int row = row0 + lk * 4 + j;
            Hp[(size_t)row * DD + col] = f2bf(acc[j] + bias);
        }
    }
}

// --- fused masked flash attention: 64-key iters, 2 sub-steps per barrier ---
// grid = 512: kq = bid&7 (XCD-local), qt = bid>>3 (128 q-rows, 8 waves x 16).
// K tile [64][256] + V tile [256][64], double-buffered; 4 independent QK MFMA
// chains per barrier interval; syncs halved vs 32-key steps. (R15 best config.)
#define PSTR 40
#define KBYTES (KTILE * 256 * 2)       // 32768
#define VBYTES (256 * KTILE * 2)       // 32768
#define PBYTES (8 * 16 * PSTR * 2)     // 10240
#define BBYTES (QROWS * 32 * 4)        // 16384
#define SMEM_ATTN (2 * KBYTES + 2 * VBYTES + PBYTES + BBYTES)   // 157696
__global__ __launch_bounds__(512) void k_attn(const ushort* __restrict__ Hp,
                                              const ushort* __restrict__ Hvt,
                                              const unsigned* __restrict__ bits,
                                              ushort* __restrict__ Opart,
                                              float* __restrict__ mpart,
                                              float* __restrict__ lpart) {
    extern __shared__ char smem[];
    ushort* KlB = (ushort*)smem;                          // 2 x [64][256] swizzled
    ushort* VlB = (ushort*)(smem + 2 * KBYTES);           // 2 x [256][64] swizzled
    ushort* Pl  = (ushort*)(smem + 2 * KBYTES + 2 * VBYTES);
    unsigned* Bl = (unsigned*)(smem + 2 * KBYTES + 2 * VBYTES + PBYTES);

    const int tid = threadIdx.x;
    const int w = tid >> 6;
    const int lane = tid & 63;
    const int lr = lane & 15;
    const int lk = lane >> 4;
    const int bid = blockIdx.x;
    const int kq = bid & 7;
    const int qt = bid >> 3;
    const int rw0 = qt * QROWS + w * 16;
    const int kstart = kq * KEYS;

    // ---- loop-invariant staging offsets (2048 16B slots each, 4 insts/thread) ----
    int kSrc[4], vSrc[4], dstO[4];
#pragma unroll
    for (int i = 0; i < 4; ++i) {
        int S = i * 512 + tid;
        int rK = S >> 5, cpK = S & 31;
        kSrc[i] = rK * 256 + (cpK ^ (rK & 7)) * 8;
        int rV = S >> 3, cpV = S & 7;
        vSrc[i] = rV * NN + (cpV ^ (rV & 7)) * 8;
        dstO[i] = S * 8;
    }
    auto stageK = [&](int buf, int kb) {
        const ushort* Kg = Hp + (size_t)kb * DD;
        ushort* base = KlB + buf * (KTILE * 256);
#pragma unroll
        for (int i = 0; i < 4; ++i) gl_lds16(Kg + kSrc[i], base + dstO[i]);
    };
    auto stageV = [&](int buf, int kb) {
        const ushort* Vg = Hvt + kb;
        ushort* base = VlB + buf * (256 * KTILE);
#pragma unroll
        for (int i = 0; i < 4; ++i) gl_lds16(Vg + vSrc[i], base + dstO[i]);
    };

    // ---- loop-invariant LDS read offsets (bytes) ----
    int Koff[8];
#pragma unroll
    for (int kk = 0; kk < 8; ++kk)
        Koff[kk] = (lr << 9) + ((((kk << 2) + lk) ^ (lr & 7)) << 4);
    const int vBaseA = (lr << 7) + ((lk ^ (lr & 7)) << 4);
    const int vBaseB = (lr << 7) + (((4 + lk) ^ (lr & 7)) << 4);

    short8 qf[8];
#pragma unroll
    for (int kk = 0; kk < 8; ++kk)
        qf[kk] = *reinterpret_cast<const short8*>(Hp + (size_t)(rw0 + lr) * DD + kk * 32 + lk * 8);

    f32x4 o[17];
#pragma unroll
    for (int t = 0; t < 17; ++t) o[t] = {0.f, 0.f, 0.f, 0.f};
    float m[4] = {-1e30f, -1e30f, -1e30f, -1e30f};

    short8 ones;
#pragma unroll
    for (int e = 0; e < 8; ++e) ones[e] = (short)0x3f80;  // bf16 1.0

    // ---- prologue: stage bits + tile 0 ----
    {
        const unsigned* Bg = bits + (size_t)(qt * QROWS) * (NN / 32) + kq * 32;
#pragma unroll
        for (int i = 0; i < 2; ++i) {
            int S = i * 512 + tid;
            int r = S >> 3, c = S & 7;
            gl_lds16(Bg + (size_t)r * (NN / 32) + c * 4, Bl + S * 4);
        }
    }
    stageK(0, kstart);
    stageV(0, kstart);
    asm volatile("s_waitcnt vmcnt(0)" ::: "memory");
    __builtin_amdgcn_s_barrier();
    __builtin_amdgcn_sched_barrier(0);

    ushort* Pw = Pl + (size_t)w * 16 * PSTR;
    const int mrow = (w * 16 + lk * 4) * 32;
    int cur = 0;
    for (int it = 0; it < ITERS; ++it) {
        const int kb = kstart + it * KTILE;
        const bool staged = (it + 1 < ITERS);
        if (staged) {                       // 2-buffer: stage next 64-key tile
            stageK(cur ^ 1, kb + KTILE);
            stageV(cur ^ 1, kb + KTILE);
        }
        unsigned mwa[4], mwb[4];
#pragma unroll
        for (int j = 0; j < 4; ++j) {
            mwa[j] = Bl[mrow + j * 32 + it * 2];
            mwb[j] = Bl[mrow + j * 32 + it * 2 + 1];
        }

        // ---- QK^T for BOTH sub-tiles (4 independent MFMA chains) ----
        const char* Kb = (const char*)(KlB + cur * (KTILE * 256));
        f32x4 s0a = {0.f,0.f,0.f,0.f}, s1a = {0.f,0.f,0.f,0.f};
        f32x4 s0b = {0.f,0.f,0.f,0.f}, s1b = {0.f,0.f,0.f,0.f};
        __builtin_amdgcn_s_setprio(1);
#pragma unroll
        for (int kk = 0; kk < 8; ++kk) {
            short8 k0a = *reinterpret_cast<const short8*>(Kb + Koff[kk]);
            short8 k1a = *reinterpret_cast<const short8*>(Kb + Koff[kk] + (16 << 9));
            short8 k0b = *reinterpret_cast<const short8*>(Kb + Koff[kk] + (32 << 9));
            short8 k1b = *reinterpret_cast<const short8*>(Kb + Koff[kk] + (48 << 9));
            s0a = __builtin_amdgcn_mfma_f32_16x16x32_bf16(qf[kk], k0a, s0a, 0, 0, 0);
            s1a = __builtin_amdgcn_mfma_f32_16x16x32_bf16(qf[kk], k1a, s1a, 0, 0, 0);
            s0b = __builtin_amdgcn_mfma_f32_16x16x32_bf16(qf[kk], k0b, s0b, 0, 0, 0);
            s1b = __builtin_amdgcn_mfma_f32_16x16x32_bf16(qf[kk], k1b, s1b, 0, 0, 0);
        }
        __builtin_amdgcn_s_setprio(0);

        const char* Vb = (const char*)(VlB + cur * (256 * KTILE));
        // ================= sub-step A =================
        {
            float c = -1e30f;
#pragma unroll
            for (int j = 0; j < 4; ++j) {
                float a0 = ((mwa[j] >> lr) & 1u) ? s0a[j] : -1e30f;
                float a1 = ((mwa[j] >> (lr + 16)) & 1u) ? s1a[j] : -1e30f;
                s0a[j] = a0; s1a[j] = a1;
                c = fmaxf(c, fmaxf(a0, a1) - m[j]);
            }
            if (__any(c > THR)) {
#pragma unroll
                for (int j = 0; j < 4; ++j) {
                    float mx = fmaxf(s0a[j], s1a[j]);
                    mx = fmaxf(mx, __shfl_xor(mx, 1));
                    mx = fmaxf(mx, __shfl_xor(mx, 2));
                    mx = fmaxf(mx, __shfl_xor(mx, 4));
                    mx = fmaxf(mx, __shfl_xor(mx, 8));
                    float mn = fmaxf(m[j], mx);
                    float scale = __expf(m[j] - mn);
                    m[j] = mn;
#pragma unroll
                    for (int t = 0; t < 17; ++t) o[t][j] *= scale;
                }
            }
#pragma unroll
            for (int j = 0; j < 4; ++j) {
                Pw[(lk * 4 + j) * PSTR + lr]      = f2bf(__expf(s0a[j] - m[j]));
                Pw[(lk * 4 + j) * PSTR + 16 + lr] = f2bf(__expf(s1a[j] - m[j]));
            }
            asm volatile("s_waitcnt lgkmcnt(0)" ::: "memory");
            __builtin_amdgcn_sched_barrier(0);
            short8 pa = *reinterpret_cast<const short8*>(Pw + lr * PSTR + lk * 8);
            __builtin_amdgcn_s_setprio(1);
#pragma unroll
            for (int t = 0; t < 16; ++t) {
                short8 vf = *reinterpret_cast<const short8*>(Vb + vBaseA + (t << 11));
                o[t] = __builtin_amdgcn_mfma_f32_16x16x32_bf16(pa, vf, o[t], 0, 0, 0);
            }
            o[16] = __builtin_amdgcn_mfma_f32_16x16x32_bf16(pa, ones, o[16], 0, 0, 0);
            __builtin_amdgcn_s_setprio(0);
        }
        // ================= sub-step B =================
        {
            float c = -1e30f;
#pragma unroll
            for (int j = 0; j < 4; ++j) {
                float a0 = ((mwb[j] >> lr) & 1u) ? s0b[j] : -1e30f;
                float a1 = ((mwb[j] >> (lr + 16)) & 1u) ? s1b[j] : -1e30f;
                s0b[j] = a0; s1b[j] = a1;
                c = fmaxf(c, fmaxf(a0, a1) - m[j]);
            }
            if (__any(c > THR)) {
#pragma unroll
                for (int j = 0; j < 4; ++j) {
                    float mx = fmaxf(s0b[j], s1b[j]);
                    mx = fmaxf(mx, __shfl_xor(mx, 1));
                    mx = fmaxf(mx, __shfl_xor(mx, 2));
                    mx = fmaxf(mx, __shfl_xor(mx, 4));
                    mx = fmaxf(mx, __shfl_xor(mx, 8));
                    float mn = fmaxf(m[j], mx);
                    float scale = __expf(m[j] - mn);
                    m[j] = mn;
#pragma unroll
                    for (int t = 0; t < 17; ++t) o[t][j] *= scale;
                }
            }
#pragma unroll
            for (int j = 0; j < 4; ++j) {
                Pw[(lk * 4 + j) * PSTR + lr]      = f2bf(__expf(s0b[j] - m[j]));
                Pw[(lk * 4 + j) * PSTR + 16 + lr] = f2bf(__expf(s1b[j] - m[j]));
            }
            asm volatile("s_waitcnt lgkmcnt(0)" ::: "memory");
            __builtin_amdgcn_sched_barrier(0);
            short8 pb = *reinterpret_cast<const short8*>(Pw + lr * PSTR + lk * 8);
            __builtin_amdgcn_s_setprio(1);
#pragma unroll
            for (int t = 0; t < 16; ++t) {
                short8 vf = *reinterpret_cast<const short8*>(Vb + vBaseB + (t << 11));
                o[t] = __builtin_amdgcn_mfma_f32_16x16x32_bf16(pb, vf, o[t], 0, 0, 0);
            }
            o[16] = __builtin_amdgcn_mfma_f32_16x16x32_bf16(pb, ones, o[16], 0, 0, 0);
            __builtin_amdgcn_s_setprio(0);
        }
        // end of iter: next tile must be resident (issued a full iter ago)
        if (staged) {
            asm volatile("s_waitcnt vmcnt(0)" ::: "memory");
            __builtin_amdgcn_s_barrier();
            __builtin_amdgcn_sched_barrier(0);
        }
        cur ^= 1;
    }

    // ---- write split-K partials ----
    ushort* op = Opart + ((size_t)kq * NN + rw0) * DD;
#pragma unroll
    for (int t = 0; t < 16; ++t)
#pragma unroll
        for (int j = 0; j < 4; ++j)
            op[(size_t)(lk * 4 + j) * DD + t * 16 + lr] = f2bf(o[t][j]);
    if (lr == 0) {
#pragma unroll
        for (int j = 0; j < 4; ++j) {
            mpart[kq * NN + rw0 + lk * 4 + j] = m[j];
            lpart[kq * NN + rw0 + lk * 4 + j] = o[16][j];
        }
    }
}

// --- merge 8 split-K partials + CRF epilogue ---
__global__ __launch_bounds__(256) void k_merge8(const ushort* __restrict__ Opart,
                                                const float* __restrict__ mpart,
                                                const float* __restrict__ lpart,
                                                const float* __restrict__ Qo,
                                                float* __restrict__ dst) {
    int w = threadIdx.x >> 6;
    int lane = threadIdx.x & 63;
    int r0 = blockIdx.x * 32 + w * 8;
    for (int rr = 0; rr < 8; ++rr) {
        int r = r0 + rr;
        float mv[8], f[8];
        float M = -1e30f;
#pragma unroll
        for (int p = 0; p < 8; ++p) { mv[p] = mpart[p * NN + r]; M = fmaxf(M, mv[p]); }
        float L = 0.f;
#pragma unroll
        for (int p = 0; p < 8; ++p) { f[p] = __expf(mv[p] - M); L += f[p] * lpart[p * NN + r]; }
        float invL = 1.0f / L;
        int c = lane * 4;
        float a0 = 0.f, a1 = 0.f, a2 = 0.f, a3 = 0.f;
#pragma unroll
        for (int p = 0; p < 8; ++p) {
            ushort4 u = *reinterpret_cast<const ushort4*>(Opart + ((size_t)p * NN + r) * DD + c);
            a0 += f[p] * bf2f(u.x); a1 += f[p] * bf2f(u.y);
            a2 += f[p] * bf2f(u.z); a3 += f[p] * bf2f(u.w);
        }
        float4 qv = *reinterpret_cast<const float4*>(Qo + (size_t)r * DD + c);
        float4 ov;
        ov.x = (ALPHA * qv.x + a0 * invL) * (1.0f / (ALPHA + BETA));
        ov.y = (ALPHA * qv.y + a1 * invL) * (1.0f / (ALPHA + BETA));
        ov.z = (ALPHA * qv.z + a2 * invL) * (1.0f / (ALPHA + BETA));
        ov.w = (ALPHA * qv.w + a3 * invL) * (1.0f / (ALPHA + BETA));
        *reinterpret_cast<float4*>(dst + (size_t)r * DD + c) = ov;
    }
}

extern "C" void kernel_launch(void* const* d_in, const int* in_sizes, int n_in,
                              void* d_out, int out_size, void* d_ws, size_t ws_size,
                              hipStream_t stream) {
    const float* Q   = (const float*)d_in[0];
    const float* sim = (const float*)d_in[1];
    const float* W   = (const float*)d_in[2];
    const float* b   = (const float*)d_in[3];
    float* out = (float*)d_out;

    char* ws = (char*)d_ws;
    size_t off = 0;
    ushort* Hv   = (ushort*)(ws + off); off += (size_t)NN * DD * 2;
    ushort* HvtA = (ushort*)(ws + off); off += (size_t)NN * DD * 2;
    ushort* HvtB = (ushort*)(ws + off); off += (size_t)NN * DD * 2;
    ushort* Hp   = (ushort*)(ws + off); off += (size_t)NN * DD * 2;
    ushort* Wb   = (ushort*)(ws + off); off += (size_t)DD * DD * 2;
    unsigned* bits = (unsigned*)(ws + off); off += (size_t)NN * (NN / 32) * 4;
    float*  H1   = (float*)(ws + off);  off += (size_t)NN * DD * 4;
    ushort* Opart = (ushort*)(ws + off); off += (size_t)KQ * NN * DD * 2;
    float*  mpart = (float*)(ws + off);  off += (size_t)KQ * NN * 4;
    float*  lpart = (float*)(ws + off);  off += (size_t)KQ * NN * 4;

    (void)hipFuncSetAttribute((const void*)k_attn,
                              hipFuncAttributeMaxDynamicSharedMemorySize, SMEM_ATTN);

    k_wconv<<<DD * DD / 256, 256, 0, stream>>>(W, Wb);
    k_pack<<<NN, 256, 0, stream>>>(sim, bits);
    k_convert<<<(NN / 64) * (DD / 64), 256, 0, stream>>>(Q, Hv, HvtA);

    // iter 1: V = Q (HvtA)
    k_proj<<<NN / 32, 256, 0, stream>>>(Hv, Wb, b, Hp);
    k_attn<<<(NN / QROWS) * KQ, 512, SMEM_ATTN, stream>>>(Hp, HvtA, bits, Opart, mpart, lpart);
    k_merge8<<<NN / 32, 256, 0, stream>>>(Opart, mpart, lpart, Q, H1);
    k_convert<<<(NN / 64) * (DD / 64), 256, 0, stream>>>(H1, Hv, HvtB);

    // iter 2: V = H1 (HvtB)
    k_proj<<<NN / 32, 256, 0, stream>>>(Hv, Wb, b, Hp);
    k_attn<<<(NN / QROWS) * KQ, 512, SMEM_ATTN, stream>>>(Hp, HvtB, bits, Opart, mpart, lpart);
    k_merge8<<<NN / 32, 256, 0, stream>>>(Opart, mpart, lpart, Q, out);
}

// Round 20
// 296.556 us; speedup vs baseline: 2.7472x; 1.1147x over previous
//
#include <hip/hip_runtime.h>
#include <hip/hip_bf16.h>

#define NN 8192
#define DD 256
#define ALPHA 50.0f
#define BETA 1.0f
#define THR 10.0f
#define KQ 4                 // key splits (one per XCD-pair; 1 block/CU total)
#define KEYS (NN / KQ)       // 2048 keys per split
#define KTILE 64             // keys per iteration (2 sub-steps of 32)
#define ITERS (KEYS / KTILE) // 32
#define QROWS 128            // q-rows per block (8 waves x 16)

typedef __attribute__((ext_vector_type(8))) short short8;
typedef __attribute__((ext_vector_type(4))) float f32x4;

static __device__ __forceinline__ ushort f2bf(float f) {
    union { __hip_bfloat16 h; ushort u; } v;
    v.h = __float2bfloat16(f);
    return v.u;
}
static __device__ __forceinline__ float bf2f(ushort u) {
    union { unsigned u; float f; } v; v.u = ((unsigned)u) << 16;
    return v.f;
}
static __device__ __forceinline__ void gl_lds16(const void* g, void* l) {
    __builtin_amdgcn_global_load_lds(
        (const __attribute__((address_space(1))) unsigned int*)g,
        (__attribute__((address_space(3))) unsigned int*)l, 16, 0, 0);
}

// --- W f32 -> bf16, once ---
__global__ void k_wconv(const float* __restrict__ W, ushort* __restrict__ Wb) {
    int i = blockIdx.x * 256 + threadIdx.x;
    Wb[i] = f2bf(W[i]);
}

// --- bitpack mask: bits[row][col/32]; float4 loads + LDS nibble assembly ---
__global__ __launch_bounds__(256) void k_pack(const float* __restrict__ sim,
                                              unsigned* __restrict__ bits) {
    __shared__ unsigned char nibs[256];
    int row = blockIdx.x;
    int tid = threadIdx.x;
    for (int p = 0; p < 8; ++p) {
        int col = p * 1024 + tid * 4;
        float4 v = *reinterpret_cast<const float4*>(sim + (size_t)row * NN + col);
        unsigned char nib = (unsigned char)((v.x != 0.f) | ((v.y != 0.f) << 1) |
                                            ((v.z != 0.f) << 2) | ((v.w != 0.f) << 3));
        nibs[tid] = nib;
        __syncthreads();
        if (tid < 32) {
            unsigned word = 0;
#pragma unroll
            for (int i = 0; i < 8; ++i) word |= ((unsigned)nibs[tid * 8 + i]) << (4 * i);
            bits[row * (NN / 32) + p * 32 + tid] = word;
        }
        __syncthreads();
    }
}

// --- H f32 -> Hv bf16 (row-major) and Hvt bf16 (transposed [D][N]) ---
__global__ __launch_bounds__(256) void k_convert(const float* __restrict__ H,
                                                 ushort* __restrict__ Hv,
                                                 ushort* __restrict__ Hvt) {
    __shared__ ushort T[64][72];
    int tile = blockIdx.x;
    int r0 = (tile >> 2) * 64;
    int c0 = (tile & 3) * 64;
    int tid = threadIdx.x;
    int tr = tid >> 4;
    int tc = (tid & 15) * 4;
    for (int i = 0; i < 4; ++i) {
        int r = tr + i * 16;
        float4 v = *reinterpret_cast<const float4*>(H + (size_t)(r0 + r) * DD + c0 + tc);
        ushort4 o;
        o.x = f2bf(v.x); o.y = f2bf(v.y); o.z = f2bf(v.z); o.w = f2bf(v.w);
        *reinterpret_cast<ushort4*>(Hv + (size_t)(r0 + r) * DD + c0 + tc) = o;
        T[tc + 0][r] = o.x; T[tc + 1][r] = o.y; T[tc + 2][r] = o.z; T[tc + 3][r] = o.w;
    }
    __syncthreads();
    for (int i = 0; i < 4; ++i) {
        int c = tr + i * 16;
        ushort4 o;
        o.x = T[c][tc + 0]; o.y = T[c][tc + 1]; o.z = T[c][tc + 2]; o.w = T[c][tc + 3];
        *reinterpret_cast<ushort4*>(Hvt + (size_t)(c0 + c) * NN + r0 + tc) = o;
    }
}

// --- Hp = bf16(Hv @ W^T + b) ---
__global__ __launch_bounds__(256) void k_proj(const ushort* __restrict__ Hv,
                                              const ushort* __restrict__ Wb,
                                              const float* __restrict__ b,
                                              ushort* __restrict__ Hp) {
    int w = threadIdx.x >> 6;
    int lane = threadIdx.x & 63;
    int row0 = (blockIdx.x >> 1) * 64 + w * 16;
    int ch = blockIdx.x & 1;
    int lr = lane & 15;
    int lk = lane >> 4;
    short8 af[8];
    for (int kk = 0; kk < 8; ++kk)
        af[kk] = *reinterpret_cast<const short8*>(Hv + (size_t)(row0 + lr) * DD + kk * 32 + lk * 8);
    for (int t = 0; t < 8; ++t) {
        f32x4 acc = {0.f, 0.f, 0.f, 0.f};
        int col = (ch * 8 + t) * 16 + lr;
        for (int kk = 0; kk < 8; ++kk) {
            short8 bf = *reinterpret_cast<const short8*>(Wb + (size_t)col * DD + kk * 32 + lk * 8);
            acc = __builtin_amdgcn_mfma_f32_16x16x32_bf16(af[kk], bf, acc, 0, 0, 0);
        }
        float bias = b[col];
        for (int j = 0; j < 4; ++j) {
            int row = row0 + lk * 4 + j;
            Hp[(size_t)row * DD + col] = f2bf(acc[j] + bias);
        }
    }
}

// --- fused masked flash attention: 64-key iters, 2 sub-steps per barrier ---
// grid = 256 (= 1 block/CU, single visit): kq = bid&3, qt = bid>>2.
// XCD sees a single kq range (K/V ~2 MB, L2-resident). R15 inner loop.
#define PSTR 40
#define KBYTES (KTILE * 256 * 2)       // 32768
#define VBYTES (256 * KTILE * 2)       // 32768
#define PBYTES (8 * 16 * PSTR * 2)     // 10240
#define SMEM_ATTN (2 * KBYTES + 2 * VBYTES + PBYTES)   // 141312
__global__ __launch_bounds__(512) void k_attn(const ushort* __restrict__ Hp,
                                              const ushort* __restrict__ Hvt,
                                              const unsigned* __restrict__ bits,
                                              ushort* __restrict__ Opart,
                                              float* __restrict__ mpart,
                                              float* __restrict__ lpart) {
    extern __shared__ char smem[];
    ushort* KlB = (ushort*)smem;                          // 2 x [64][256] swizzled
    ushort* VlB = (ushort*)(smem + 2 * KBYTES);           // 2 x [256][64] swizzled
    ushort* Pl  = (ushort*)(smem + 2 * KBYTES + 2 * VBYTES);

    const int tid = threadIdx.x;
    const int w = tid >> 6;
    const int lane = tid & 63;
    const int lr = lane & 15;
    const int lk = lane >> 4;
    const int bid = blockIdx.x;
    const int kq = bid & 3;
    const int qt = bid >> 2;
    const int rw0 = qt * QROWS + w * 16;
    const int kstart = kq * KEYS;

    // ---- loop-invariant staging offsets (2048 16B slots each, 4 insts/thread) ----
    int kSrc[4], vSrc[4], dstO[4];
#pragma unroll
    for (int i = 0; i < 4; ++i) {
        int S = i * 512 + tid;
        int rK = S >> 5, cpK = S & 31;
        kSrc[i] = rK * 256 + (cpK ^ (rK & 7)) * 8;
        int rV = S >> 3, cpV = S & 7;
        vSrc[i] = rV * NN + (cpV ^ (rV & 7)) * 8;
        dstO[i] = S * 8;
    }
    auto stageK = [&](int buf, int kb) {
        const ushort* Kg = Hp + (size_t)kb * DD;
        ushort* base = KlB + buf * (KTILE * 256);
#pragma unroll
        for (int i = 0; i < 4; ++i) gl_lds16(Kg + kSrc[i], base + dstO[i]);
    };
    auto stageV = [&](int buf, int kb) {
        const ushort* Vg = Hvt + kb;
        ushort* base = VlB + buf * (256 * KTILE);
#pragma unroll
        for (int i = 0; i < 4; ++i) gl_lds16(Vg + vSrc[i], base + dstO[i]);
    };

    // ---- loop-invariant LDS read offsets (bytes) ----
    int Koff[8];
#pragma unroll
    for (int kk = 0; kk < 8; ++kk)
        Koff[kk] = (lr << 9) + ((((kk << 2) + lk) ^ (lr & 7)) << 4);
    const int vBaseA = (lr << 7) + ((lk ^ (lr & 7)) << 4);
    const int vBaseB = (lr << 7) + (((4 + lk) ^ (lr & 7)) << 4);

    short8 qf[8];
#pragma unroll
    for (int kk = 0; kk < 8; ++kk)
        qf[kk] = *reinterpret_cast<const short8*>(Hp + (size_t)(rw0 + lr) * DD + kk * 32 + lk * 8);

    f32x4 o[17];
#pragma unroll
    for (int t = 0; t < 17; ++t) o[t] = {0.f, 0.f, 0.f, 0.f};
    float m[4] = {-1e30f, -1e30f, -1e30f, -1e30f};

    short8 ones;
#pragma unroll
    for (int e = 0; e < 8; ++e) ones[e] = (short)0x3f80;  // bf16 1.0

    // ---- prologue: stage tile 0 ----
    stageK(0, kstart);
    stageV(0, kstart);
    asm volatile("s_waitcnt vmcnt(0)" ::: "memory");
    __builtin_amdgcn_s_barrier();
    __builtin_amdgcn_sched_barrier(0);

    ushort* Pw = Pl + (size_t)w * 16 * PSTR;
    const int rowbase = (rw0 + lk * 4) * (NN / 32);
    int cur = 0;
    for (int it = 0; it < ITERS; ++it) {
        const int kb = kstart + it * KTILE;
        const bool staged = (it + 1 < ITERS);
        if (staged) {                       // 2-buffer: stage next 64-key tile
            stageK(cur ^ 1, kb + KTILE);
            stageV(cur ^ 1, kb + KTILE);
        }
        const int wi = kb >> 5;
        unsigned mwa[4], mwb[4];
#pragma unroll
        for (int j = 0; j < 4; ++j) {
            mwa[j] = bits[rowbase + j * (NN / 32) + wi];
            mwb[j] = bits[rowbase + j * (NN / 32) + wi + 1];
        }

        // ---- QK^T for BOTH sub-tiles (4 independent MFMA chains) ----
        const char* Kb = (const char*)(KlB + cur * (KTILE * 256));
        f32x4 s0a = {0.f,0.f,0.f,0.f}, s1a = {0.f,0.f,0.f,0.f};
        f32x4 s0b = {0.f,0.f,0.f,0.f}, s1b = {0.f,0.f,0.f,0.f};
        __builtin_amdgcn_s_setprio(1);
#pragma unroll
        for (int kk = 0; kk < 8; ++kk) {
            short8 k0a = *reinterpret_cast<const short8*>(Kb + Koff[kk]);
            short8 k1a = *reinterpret_cast<const short8*>(Kb + Koff[kk] + (16 << 9));
            short8 k0b = *reinterpret_cast<const short8*>(Kb + Koff[kk] + (32 << 9));
            short8 k1b = *reinterpret_cast<const short8*>(Kb + Koff[kk] + (48 << 9));
            s0a = __builtin_amdgcn_mfma_f32_16x16x32_bf16(qf[kk], k0a, s0a, 0, 0, 0);
            s1a = __builtin_amdgcn_mfma_f32_16x16x32_bf16(qf[kk], k1a, s1a, 0, 0, 0);
            s0b = __builtin_amdgcn_mfma_f32_16x16x32_bf16(qf[kk], k0b, s0b, 0, 0, 0);
            s1b = __builtin_amdgcn_mfma_f32_16x16x32_bf16(qf[kk], k1b, s1b, 0, 0, 0);
        }
        __builtin_amdgcn_s_setprio(0);

        const char* Vb = (const char*)(VlB + cur * (256 * KTILE));
        // ================= sub-step A =================
        {
            float c = -1e30f;
#pragma unroll
            for (int j = 0; j < 4; ++j) {
                float a0 = ((mwa[j] >> lr) & 1u) ? s0a[j] : -1e30f;
                float a1 = ((mwa[j] >> (lr + 16)) & 1u) ? s1a[j] : -1e30f;
                s0a[j] = a0; s1a[j] = a1;
                c = fmaxf(c, fmaxf(a0, a1) - m[j]);
            }
            if (__any(c > THR)) {
#pragma unroll
                for (int j = 0; j < 4; ++j) {
                    float mx = fmaxf(s0a[j], s1a[j]);
                    mx = fmaxf(mx, __shfl_xor(mx, 1));
                    mx = fmaxf(mx, __shfl_xor(mx, 2));
                    mx = fmaxf(mx, __shfl_xor(mx, 4));
                    mx = fmaxf(mx, __shfl_xor(mx, 8));
                    float mn = fmaxf(m[j], mx);
                    float scale = __expf(m[j] - mn);
                    m[j] = mn;
#pragma unroll
                    for (int t = 0; t < 17; ++t) o[t][j] *= scale;
                }
            }
#pragma unroll
            for (int j = 0; j < 4; ++j) {
                Pw[(lk * 4 + j) * PSTR + lr]      = f2bf(__expf(s0a[j] - m[j]));
                Pw[(lk * 4 + j) * PSTR + 16 + lr] = f2bf(__expf(s1a[j] - m[j]));
            }
            asm volatile("s_waitcnt lgkmcnt(0)" ::: "memory");
            __builtin_amdgcn_sched_barrier(0);
            short8 pa = *reinterpret_cast<const short8*>(Pw + lr * PSTR + lk * 8);
            __builtin_amdgcn_s_setprio(1);
#pragma unroll
            for (int t = 0; t < 16; ++t) {
                short8 vf = *reinterpret_cast<const short8*>(Vb + vBaseA + (t << 11));
                o[t] = __builtin_amdgcn_mfma_f32_16x16x32_bf16(pa, vf, o[t], 0, 0, 0);
            }
            o[16] = __builtin_amdgcn_mfma_f32_16x16x32_bf16(pa, ones, o[16], 0, 0, 0);
            __builtin_amdgcn_s_setprio(0);
        }
        // ================= sub-step B =================
        {
            float c = -1e30f;
#pragma unroll
            for (int j = 0; j < 4; ++j) {
                float a0 = ((mwb[j] >> lr) & 1u) ? s0b[j] : -1e30f;
                float a1 = ((mwb[j] >> (lr + 16)) & 1u) ? s1b[j] : -1e30f;
                s0b[j] = a0; s1b[j] = a1;
                c = fmaxf(c, fmaxf(a0, a1) - m[j]);
            }
            if (__any(c > THR)) {
#pragma unroll
                for (int j = 0; j < 4; ++j) {
                    float mx = fmaxf(s0b[j], s1b[j]);
                    mx = fmaxf(mx, __shfl_xor(mx, 1));
                    mx = fmaxf(mx, __shfl_xor(mx, 2));
                    mx = fmaxf(mx, __shfl_xor(mx, 4));
                    mx = fmaxf(mx, __shfl_xor(mx, 8));
                    float mn = fmaxf(m[j], mx);
                    float scale = __expf(m[j] - mn);
                    m[j] = mn;
#pragma unroll
                    for (int t = 0; t < 17; ++t) o[t][j] *= scale;
                }
            }
#pragma unroll
            for (int j = 0; j < 4; ++j) {
                Pw[(lk * 4 + j) * PSTR + lr]      = f2bf(__expf(s0b[j] - m[j]));
                Pw[(lk * 4 + j) * PSTR + 16 + lr] = f2bf(__expf(s1b[j] - m[j]));
            }
            asm volatile("s_waitcnt lgkmcnt(0)" ::: "memory");
            __builtin_amdgcn_sched_barrier(0);
            short8 pb = *reinterpret_cast<const short8*>(Pw + lr * PSTR + lk * 8);
            __builtin_amdgcn_s_setprio(1);
#pragma unroll
            for (int t = 0; t < 16; ++t) {
                short8 vf = *reinterpret_cast<const short8*>(Vb + vBaseB + (t << 11));
                o[t] = __builtin_amdgcn_mfma_f32_16x16x32_bf16(pb, vf, o[t], 0, 0, 0);
            }
            o[16] = __builtin_amdgcn_mfma_f32_16x16x32_bf16(pb, ones, o[16], 0, 0, 0);
            __builtin_amdgcn_s_setprio(0);
        }
        // end of iter: next tile must be resident (issued a full iter ago)
        if (staged) {
            asm volatile("s_waitcnt vmcnt(0)" ::: "memory");
            __builtin_amdgcn_s_barrier();
            __builtin_amdgcn_sched_barrier(0);
        }
        cur ^= 1;
    }

    // ---- write split-K partials ----
    ushort* op = Opart + ((size_t)kq * NN + rw0) * DD;
#pragma unroll
    for (int t = 0; t < 16; ++t)
#pragma unroll
        for (int j = 0; j < 4; ++j)
            op[(size_t)(lk * 4 + j) * DD + t * 16 + lr] = f2bf(o[t][j]);
    if (lr == 0) {
#pragma unroll
        for (int j = 0; j < 4; ++j) {
            mpart[kq * NN + rw0 + lk * 4 + j] = m[j];
            lpart[kq * NN + rw0 + lk * 4 + j] = o[16][j];
        }
    }
}

// --- merge 4 split-K partials + CRF epilogue; optionally emit f32 out and/or
// bf16 H (row-major + transposed) for the next iteration (fuses k_convert) ---
__global__ __launch_bounds__(256) void k_merge4(const ushort* __restrict__ Opart,
                                                const float* __restrict__ mpart,
                                                const float* __restrict__ lpart,
                                                const float* __restrict__ Qo,
                                                float* __restrict__ dst,
                                                ushort* __restrict__ HvOut,
                                                ushort* __restrict__ HvtOut) {
    __shared__ ushort T[32][264];
    int w = threadIdx.x >> 6;
    int lane = threadIdx.x & 63;
    int r0 = blockIdx.x * 32 + w * 8;
    for (int rr = 0; rr < 8; ++rr) {
        int r = r0 + rr;
        float mv[KQ], f[KQ];
        float M = -1e30f;
#pragma unroll
        for (int p = 0; p < KQ; ++p) { mv[p] = mpart[p * NN + r]; M = fmaxf(M, mv[p]); }
        float L = 0.f;
#pragma unroll
        for (int p = 0; p < KQ; ++p) { f[p] = __expf(mv[p] - M); L += f[p] * lpart[p * NN + r]; }
        float invL = 1.0f / L;
        int c = lane * 4;
        float a0 = 0.f, a1 = 0.f, a2 = 0.f, a3 = 0.f;
#pragma unroll
        for (int p = 0; p < KQ; ++p) {
            ushort4 u = *reinterpret_cast<const ushort4*>(Opart + ((size_t)p * NN + r) * DD + c);
            a0 += f[p] * bf2f(u.x); a1 += f[p] * bf2f(u.y);
            a2 += f[p] * bf2f(u.z); a3 += f[p] * bf2f(u.w);
        }
        float4 qv = *reinterpret_cast<const float4*>(Qo + (size_t)r * DD + c);
        float4 ov;
        ov.x = (ALPHA * qv.x + a0 * invL) * (1.0f / (ALPHA + BETA));
        ov.y = (ALPHA * qv.y + a1 * invL) * (1.0f / (ALPHA + BETA));
        ov.z = (ALPHA * qv.z + a2 * invL) * (1.0f / (ALPHA + BETA));
        ov.w = (ALPHA * qv.w + a3 * invL) * (1.0f / (ALPHA + BETA));
        if (dst) *reinterpret_cast<float4*>(dst + (size_t)r * DD + c) = ov;
        ushort4 bv;
        bv.x = f2bf(ov.x); bv.y = f2bf(ov.y); bv.z = f2bf(ov.z); bv.w = f2bf(ov.w);
        if (HvOut) *reinterpret_cast<ushort4*>(HvOut + (size_t)r * DD + c) = bv;
        if (HvtOut) {
            int rl = w * 8 + rr;
            T[rl][c] = bv.x; T[rl][c + 1] = bv.y; T[rl][c + 2] = bv.z; T[rl][c + 3] = bv.w;
        }
    }
    if (HvtOut) {
        __syncthreads();
        int col = threadIdx.x;       // 0..255 -> one Hvt row
        int R0 = blockIdx.x * 32;
        ushort* dstp = HvtOut + (size_t)col * NN + R0;
#pragma unroll
        for (int k = 0; k < 8; ++k) {
            ushort4 u;
            u.x = T[k * 4 + 0][col]; u.y = T[k * 4 + 1][col];
            u.z = T[k * 4 + 2][col]; u.w = T[k * 4 + 3][col];
            *reinterpret_cast<ushort4*>(dstp + k * 4) = u;
        }
    }
}

extern "C" void kernel_launch(void* const* d_in, const int* in_sizes, int n_in,
                              void* d_out, int out_size, void* d_ws, size_t ws_size,
                              hipStream_t stream) {
    const float* Q   = (const float*)d_in[0];
    const float* sim = (const float*)d_in[1];
    const float* W   = (const float*)d_in[2];
    const float* b   = (const float*)d_in[3];
    float* out = (float*)d_out;

    char* ws = (char*)d_ws;
    size_t off = 0;
    ushort* Hv   = (ushort*)(ws + off); off += (size_t)NN * DD * 2;
    ushort* HvtA = (ushort*)(ws + off); off += (size_t)NN * DD * 2;
    ushort* HvtB = (ushort*)(ws + off); off += (size_t)NN * DD * 2;
    ushort* Hp   = (ushort*)(ws + off); off += (size_t)NN * DD * 2;
    ushort* Wb   = (ushort*)(ws + off); off += (size_t)DD * DD * 2;
    unsigned* bits = (unsigned*)(ws + off); off += (size_t)NN * (NN / 32) * 4;
    ushort* Opart = (ushort*)(ws + off); off += (size_t)KQ * NN * DD * 2;
    float*  mpart = (float*)(ws + off);  off += (size_t)KQ * NN * 4;
    float*  lpart = (float*)(ws + off);  off += (size_t)KQ * NN * 4;

    (void)hipFuncSetAttribute((const void*)k_attn,
                              hipFuncAttributeMaxDynamicSharedMemorySize, SMEM_ATTN);

    k_wconv<<<DD * DD / 256, 256, 0, stream>>>(W, Wb);
    k_pack<<<NN, 256, 0, stream>>>(sim, bits);
    k_convert<<<(NN / 64) * (DD / 64), 256, 0, stream>>>(Q, Hv, HvtA);

    // iter 1: V = Q (HvtA); merge emits bf16 H (Hv) + transposed (HvtB)
    k_proj<<<NN / 32, 256, 0, stream>>>(Hv, Wb, b, Hp);
    k_attn<<<(NN / QROWS) * KQ, 512, SMEM_ATTN, stream>>>(Hp, HvtA, bits, Opart, mpart, lpart);
    k_merge4<<<NN / 32, 256, 0, stream>>>(Opart, mpart, lpart, Q, nullptr, Hv, HvtB);

    // iter 2: V = H1 (HvtB); merge emits f32 out only
    k_proj<<<NN / 32, 256, 0, stream>>>(Hv, Wb, b, Hp);
    k_attn<<<(NN / QROWS) * KQ, 512, SMEM_ATTN, stream>>>(Hp, HvtB, bits, Opart, mpart, lpart);
    k_merge4<<<NN / 32, 256, 0, stream>>>(Opart, mpart, lpart, Q, out, nullptr, nullptr);
}